// Round 4
// baseline (301.585 us; speedup 1.0000x reference)
//
#include <hip/hip_runtime.h>
#include <hip/hip_bf16.h>
#include <stdint.h>
#include <stddef.h>

// MultiHA: y@Wq^T -> q; x@Wk^T -> k; x@Wv^T -> v; causal softmax attn; @Wp^T + bp
// B=4 S=2048 D=1024 NH=16 HS=64. All GEMM/attn compute in bf16 MFMA, f32 accum.

typedef __attribute__((ext_vector_type(4))) float f32x4;
typedef __attribute__((ext_vector_type(8))) short s16x8;
typedef __attribute__((ext_vector_type(4))) float float4v;

#define DEV __device__ __forceinline__

constexpr int Bsz = 4, Sseq = 2048, Dm = 1024, NHn = 16, HSn = 64;
// fold 1/sqrt(HS) * log2(e) into Wq so attention softmax runs in exp2 domain
constexpr float QSCALE = 0.125f * 1.4426950408889634f;

// ---- workspace layout (bytes) ----
constexpr size_t SZ_BF_XY = (size_t)Bsz * Sseq * Dm * 2;  // 16 MiB
constexpr size_t SZ_W     = (size_t)Dm * Dm * 2;          // 2 MiB
constexpr size_t OFF_XBF  = 0;
constexpr size_t OFF_YBF  = OFF_XBF + SZ_BF_XY;
constexpr size_t OFF_WQ   = OFF_YBF + SZ_BF_XY;
constexpr size_t OFF_WK   = OFF_WQ + SZ_W;
constexpr size_t OFF_WV   = OFF_WK + SZ_W;
constexpr size_t OFF_WP   = OFF_WV + SZ_W;
constexpr size_t OFF_QWS  = OFF_WP + SZ_W;   // [BH][S][64] bf16
constexpr size_t OFF_KWS  = OFF_QWS + SZ_BF_XY;
constexpr size_t OFF_VTWS = OFF_KWS + SZ_BF_XY; // [BH][64][S] bf16 (V transposed)
constexpr size_t OFF_OWS  = OFF_VTWS + SZ_BF_XY; // attn out [B][S][D] bf16
constexpr size_t OFF_FLAG = OFF_OWS + SZ_BF_XY;

DEV unsigned short f2bf(float f) {
  union { float f; unsigned int u; } v; v.f = f;
  unsigned int r = (v.u + 0x7FFFu + ((v.u >> 16) & 1u)) >> 16;
  return (unsigned short)r;
}

DEV void gll16(const void* g, void* l) {
  __builtin_amdgcn_global_load_lds((const __attribute__((address_space(1))) unsigned int*)g,
                                   (__attribute__((address_space(3))) unsigned int*)l, 16, 0, 0);
}

// ---------------- convert fp32 -> bf16 (x8 per thread) ----------------
__global__ void cvt_kernel(const float* __restrict__ src, unsigned short* __restrict__ dst,
                           int n8, float scale) {
  int i = blockIdx.x * blockDim.x + threadIdx.x;
  if (i >= n8) return;
  const float4v* s = (const float4v*)src + (size_t)i * 2;
  float4v a = s[0], b = s[1];
  s16x8 o;
  o[0] = (short)f2bf(a[0] * scale); o[1] = (short)f2bf(a[1] * scale);
  o[2] = (short)f2bf(a[2] * scale); o[3] = (short)f2bf(a[3] * scale);
  o[4] = (short)f2bf(b[0] * scale); o[5] = (short)f2bf(b[1] * scale);
  o[6] = (short)f2bf(b[2] * scale); o[7] = (short)f2bf(b[3] * scale);
  *(s16x8*)(dst + (size_t)i * 8) = o;
}

// ---------------- mask triviality flag ----------------
__global__ void init_flag(int* f) { f[0] = 1; }
__global__ void check_mask(const int* __restrict__ p, int n, int* __restrict__ f) {
  int bad = 0;
  for (int i = blockIdx.x * blockDim.x + threadIdx.x; i < n; i += gridDim.x * blockDim.x)
    bad |= (p[i] == 0);
  if (bad) atomicAnd(f, 0);
}

// ---------------- 128x128 bf16 GEMM, C[m][n] = sum_k A[m][k] * W[n][k] ----------------
// V=0: Q out bf16 [B,NH,S,HS]   V=1: K out, same layout
// V=2: Vt out bf16 [B,NH,HS,S] (LDS-transposed epilogue)
// V=3: fp32 out [M][1024] + bias
template <int V>
__global__ __launch_bounds__(256) void gemm_k(const unsigned short* __restrict__ A,
                                              const unsigned short* __restrict__ W,
                                              unsigned short* __restrict__ outb,
                                              float* __restrict__ outf,
                                              const float* __restrict__ bias) {
  constexpr int K = 1024;
  __shared__ unsigned short sm[17408]; // lA(4096) + lB(4096); V2 transpose uses 128*136
  unsigned short* lA = sm;
  unsigned short* lB = sm + 4096;
  const int tid = threadIdx.x;
  const int w = tid >> 6, lane = tid & 63, lo = lane & 15, hi = lane >> 4;
  const int wm = w >> 1, wn = w & 1;
  const int m0 = blockIdx.x * 128, n0 = blockIdx.y * 128;
  f32x4 acc[4][4] = {};

  for (int k0 = 0; k0 < K; k0 += 32) {
#pragma unroll
    for (int h = 0; h < 2; ++h) {
      int c = w * 64 + h * 256 + lane;
      gll16(A + (size_t)(m0 + (c >> 2)) * K + k0 + (c & 3) * 8, lA + (size_t)(w * 64 + h * 256) * 8);
      gll16(W + (size_t)(n0 + (c >> 2)) * K + k0 + (c & 3) * 8, lB + (size_t)(w * 64 + h * 256) * 8);
    }
    __syncthreads();
    s16x8 af[4], bfr[4];
#pragma unroll
    for (int mi = 0; mi < 4; ++mi) af[mi] = *(const s16x8*)&lA[(wm * 64 + mi * 16 + lo) * 32 + hi * 8];
#pragma unroll
    for (int ni = 0; ni < 4; ++ni) bfr[ni] = *(const s16x8*)&lB[(wn * 64 + ni * 16 + lo) * 32 + hi * 8];
#pragma unroll
    for (int mi = 0; mi < 4; ++mi)
#pragma unroll
      for (int ni = 0; ni < 4; ++ni)
        acc[mi][ni] = __builtin_amdgcn_mfma_f32_16x16x32_bf16(af[mi], bfr[ni], acc[mi][ni], 0, 0, 0);
    __syncthreads();
  }

  if constexpr (V <= 1) {
#pragma unroll
    for (int mi = 0; mi < 4; ++mi)
#pragma unroll
      for (int ni = 0; ni < 4; ++ni)
#pragma unroll
        for (int j = 0; j < 4; ++j) {
          int m = m0 + wm * 64 + mi * 16 + hi * 4 + j;
          int n = n0 + wn * 64 + ni * 16 + lo;
          int b = m >> 11, s = m & 2047, hh = n >> 6, e = n & 63;
          outb[((size_t)(b * NHn + hh) * Sseq + s) * HSn + e] = f2bf(acc[mi][ni][j]);
        }
  } else if constexpr (V == 2) {
    __syncthreads();
#pragma unroll
    for (int mi = 0; mi < 4; ++mi)
#pragma unroll
      for (int ni = 0; ni < 4; ++ni)
#pragma unroll
        for (int j = 0; j < 4; ++j) {
          int ml = wm * 64 + mi * 16 + hi * 4 + j;
          int nl = wn * 64 + ni * 16 + lo;
          sm[(size_t)nl * 136 + ml] = f2bf(acc[mi][ni][j]);
        }
    __syncthreads();
    int nl = tid >> 1, half = tid & 1;
    int b = m0 >> 11, hh = (n0 + nl) >> 6, e = (n0 + nl) & 63;
    unsigned short* dst = outb + ((size_t)(b * NHn + hh) * HSn + e) * Sseq + (m0 & 2047) + half * 64;
#pragma unroll
    for (int i = 0; i < 8; ++i)
      *(s16x8*)(dst + i * 8) = *(const s16x8*)&sm[(size_t)nl * 136 + half * 64 + i * 8];
  } else {
    float bv[4];
#pragma unroll
    for (int ni = 0; ni < 4; ++ni) bv[ni] = bias[n0 + wn * 64 + ni * 16 + lo];
#pragma unroll
    for (int mi = 0; mi < 4; ++mi)
#pragma unroll
      for (int ni = 0; ni < 4; ++ni)
#pragma unroll
        for (int j = 0; j < 4; ++j) {
          int m = m0 + wm * 64 + mi * 16 + hi * 4 + j;
          int n = n0 + wn * 64 + ni * 16 + lo;
          outf[(size_t)m * 1024 + n] = acc[mi][ni][j] + bv[ni];
        }
  }
}

// ---------------- flash attention ----------------
// R3-verified per-tile math at 16 rows/wave (mq dimension removed).
// Block (ip, bh): 64-row subtiles jA=ip, jB=31-ip -> every block does exactly
// 33 tile-computations. Grid (16,64)=1024 blocks = 4/CU resident.
// Single LDS K/V buffer + issue-early/write-late register staging (T14).
// Layouts: sreg[t][j] = S[q=qw0+hi*4+j][kpos=k0+t*16+lo],
//          oacc[et][j] = O^T[e=et*16+hi*4+j][q=qw0+lo].
DEV void attn_tile16(const unsigned short* __restrict__ kbc,
                     const unsigned short* __restrict__ vbc,
                     const s16x8 (&qf)[2], f32x4 (&oacc)[4],
                     float (&mrun)[4], float (&lrun)[4],
                     unsigned short* __restrict__ pbw, float* __restrict__ bcw,
                     int k0, int qw0, int lo, int hi, int b,
                     const int* __restrict__ pad, const int* __restrict__ tmask,
                     bool trivial) {
  // S = Q K^T  (C-layout: row q = hi*4+j, col kpos = lo)
  f32x4 sreg[4];
#pragma unroll
  for (int t = 0; t < 4; ++t) {
    f32x4 z = {0.f, 0.f, 0.f, 0.f};
#pragma unroll
    for (int kk = 0; kk < 2; ++kk) {
      s16x8 kfr = *(const s16x8*)&kbc[(t * 16 + lo) * 72 + kk * 32 + hi * 8];
      z = __builtin_amdgcn_mfma_f32_16x16x32_bf16(qf[kk], kfr, z, 0, 0, 0);
    }
    sreg[t] = z;
  }
  if (k0 + 63 > qw0) { // diagonal tiles: causal mask
#pragma unroll
    for (int t = 0; t < 4; ++t)
#pragma unroll
      for (int j = 0; j < 4; ++j) {
        int qg = qw0 + hi * 4 + j;
        int kg = k0 + t * 16 + lo;
        if (kg > qg) sreg[t][j] = -3e38f;
      }
  }
  if (!trivial) { // general pad/time masks (not hit for all-ones inputs)
#pragma unroll
    for (int t = 0; t < 4; ++t) {
      int kg = k0 + t * 16 + lo;
      int pv = pad[b * Sseq + kg];
#pragma unroll
      for (int j = 0; j < 4; ++j) {
        int qg = qw0 + hi * 4 + j;
        if (!pv || !tmask[(size_t)qg * Sseq + kg]) sreg[t][j] = -3e38f;
      }
    }
  }
  // online softmax (exp2 domain), per row j
#pragma unroll
  for (int j = 0; j < 4; ++j) {
    float mx = fmaxf(fmaxf(sreg[0][j], sreg[1][j]), fmaxf(sreg[2][j], sreg[3][j]));
    mx = fmaxf(mx, __shfl_xor(mx, 1, 64));
    mx = fmaxf(mx, __shfl_xor(mx, 2, 64));
    mx = fmaxf(mx, __shfl_xor(mx, 4, 64));
    mx = fmaxf(mx, __shfl_xor(mx, 8, 64));
    float mnew = fmaxf(mrun[j], mx);
    float al = __builtin_amdgcn_exp2f(mrun[j] - mnew);
    mrun[j] = mnew;
    float rs = 0.f;
#pragma unroll
    for (int t = 0; t < 4; ++t) {
      float p = __builtin_amdgcn_exp2f(sreg[t][j] - mnew);
      sreg[t][j] = p;
      rs += p;
    }
    rs += __shfl_xor(rs, 1, 64);
    rs += __shfl_xor(rs, 2, 64);
    rs += __shfl_xor(rs, 4, 64);
    rs += __shfl_xor(rs, 8, 64);
    lrun[j] = lrun[j] * al + rs;
    if (lo == 0) bcw[hi * 4 + j] = al;
  }
  // P -> LDS bf16 [q][kpos]
#pragma unroll
  for (int t = 0; t < 4; ++t)
#pragma unroll
    for (int j = 0; j < 4; ++j)
      pbw[(hi * 4 + j) * 72 + t * 16 + lo] = f2bf(sreg[t][j]);
  // rescale O^T accumulators (col = q = lo)
  float av = bcw[lo];
#pragma unroll
  for (int et = 0; et < 4; ++et) oacc[et] *= av;
  // O^T += V^T P^T
  s16x8 pf[2];
#pragma unroll
  for (int kk = 0; kk < 2; ++kk)
    pf[kk] = *(const s16x8*)&pbw[lo * 72 + kk * 32 + hi * 8];
#pragma unroll
  for (int et = 0; et < 4; ++et)
#pragma unroll
    for (int kk = 0; kk < 2; ++kk) {
      s16x8 vfr = *(const s16x8*)&vbc[(et * 16 + lo) * 72 + kk * 32 + hi * 8];
      oacc[et] = __builtin_amdgcn_mfma_f32_16x16x32_bf16(vfr, pf[kk], oacc[et], 0, 0, 0);
    }
}

// normalize by l and write O via per-wave LDS transpose (16 rows/wave)
DEV void attn_epilogue16(f32x4 (&oacc)[4], float (&lrun)[4],
                         unsigned short* __restrict__ pbw, float* __restrict__ bcw,
                         unsigned short* __restrict__ O, int b, int hh, int qw0,
                         int lane, int lo, int hi) {
  if (lo == 0) {
#pragma unroll
    for (int j = 0; j < 4; ++j) bcw[hi * 4 + j] = lrun[j];
  }
  float inv = 1.f / bcw[lo];
#pragma unroll
  for (int et = 0; et < 4; ++et) {
    f32x4 o = oacc[et] * inv;
#pragma unroll
    for (int j = 0; j < 4; ++j)
      pbw[lo * 72 + et * 16 + hi * 4 + j] = f2bf(o[j]);
  }
  int q = lane >> 2, seg = lane & 3;
  unsigned short* dst = O + ((size_t)b * Sseq + qw0 + q) * Dm + hh * HSn + seg * 16;
  *(s16x8*)dst = *(const s16x8*)&pbw[q * 72 + seg * 16];
  *(s16x8*)(dst + 8) = *(const s16x8*)&pbw[q * 72 + seg * 16 + 8];
}

__global__ __launch_bounds__(256, 3) void attn_kernel(const unsigned short* __restrict__ Q,
                                                      const unsigned short* __restrict__ Kg,
                                                      const unsigned short* __restrict__ Vt,
                                                      unsigned short* __restrict__ O,
                                                      const int* __restrict__ pad,
                                                      const int* __restrict__ tmask,
                                                      const int* __restrict__ flags) {
  __shared__ unsigned short kb[64 * 72];   // 9.0 KiB
  __shared__ unsigned short vb[64 * 72];   // 9.0 KiB
  __shared__ unsigned short pb[4][16 * 72]; // 9.0 KiB (wave-private P scratch)
  __shared__ float bcast[4][16];

  const int ip = blockIdx.x, bh = blockIdx.y;
  const int b = bh >> 4, hh = bh & 15;
  const int tid = threadIdx.x, w = tid >> 6, lane = tid & 63, lo = lane & 15, hi = lane >> 4;
  const int jA = ip, jB = 31 - ip;
  const int qw0A = jA * 64 + w * 16, qw0B = jB * 64 + w * 16;
  const int ktmax = jB + 1;
  const bool trivial = flags[0] != 0;

  const unsigned short* Qb = Q + (size_t)bh * Sseq * HSn;
  const unsigned short* Kb = Kg + (size_t)bh * Sseq * HSn;
  const unsigned short* Vb = Vt + (size_t)bh * HSn * Sseq;

  // Q fragments (A-operand: row=lo, k=kk*32+hi*8+e) for both subtiles
  s16x8 qfA[2], qfB[2];
#pragma unroll
  for (int kk = 0; kk < 2; ++kk) {
    qfA[kk] = *(const s16x8*)&Qb[(size_t)(qw0A + lo) * HSn + kk * 32 + hi * 8];
    qfB[kk] = *(const s16x8*)&Qb[(size_t)(qw0B + lo) * HSn + kk * 32 + hi * 8];
  }

  f32x4 oaccA[4] = {}, oaccB[4] = {};
  float mrunA[4], lrunA[4], mrunB[4], lrunB[4];
#pragma unroll
  for (int j = 0; j < 4; ++j) {
    mrunA[j] = -3e38f; lrunA[j] = 0.f;
    mrunB[j] = -3e38f; lrunB[j] = 0.f;
  }

  const int sr = tid >> 2, sc = (tid & 3) * 16;

  // prologue: stage kt=0
  s16x8 rk0, rk1, rv0, rv1;
  {
    const unsigned short* gk = Kb + (size_t)sr * HSn + sc;
    rk0 = *(const s16x8*)gk; rk1 = *(const s16x8*)(gk + 8);
    const unsigned short* gv = Vb + (size_t)sr * Sseq + sc;
    rv0 = *(const s16x8*)gv; rv1 = *(const s16x8*)(gv + 8);
  }
  *(s16x8*)&kb[sr * 72 + sc] = rk0; *(s16x8*)&kb[sr * 72 + sc + 8] = rk1;
  *(s16x8*)&vb[sr * 72 + sc] = rv0; *(s16x8*)&vb[sr * 72 + sc + 8] = rv1;
  __syncthreads();

  for (int kt = 0; kt < ktmax; ++kt) {
    const int k0 = kt * 64;
    const bool pre = (kt + 1 < ktmax);
    if (pre) { // issue next-tile loads early; latency hides under compute
      const int k1 = k0 + 64;
      const unsigned short* gk = Kb + (size_t)(k1 + sr) * HSn + sc;
      rk0 = *(const s16x8*)gk; rk1 = *(const s16x8*)(gk + 8);
      const unsigned short* gv = Vb + (size_t)sr * Sseq + k1 + sc;
      rv0 = *(const s16x8*)gv; rv1 = *(const s16x8*)(gv + 8);
    }
    if (kt <= jA)
      attn_tile16(kb, vb, qfA, oaccA, mrunA, lrunA, pb[w], bcast[w],
                  k0, qw0A, lo, hi, b, pad, tmask, trivial);
    attn_tile16(kb, vb, qfB, oaccB, mrunB, lrunB, pb[w], bcast[w],
                k0, qw0B, lo, hi, b, pad, tmask, trivial);
    __syncthreads();             // all waves done reading kb/vb
    if (pre) {                   // write-late, then make visible
      *(s16x8*)&kb[sr * 72 + sc] = rk0; *(s16x8*)&kb[sr * 72 + sc + 8] = rk1;
      *(s16x8*)&vb[sr * 72 + sc] = rv0; *(s16x8*)&vb[sr * 72 + sc + 8] = rv1;
      __syncthreads();
    }
  }

  attn_epilogue16(oaccA, lrunA, pb[w], bcast[w], O, b, hh, qw0A, lane, lo, hi);
  attn_epilogue16(oaccB, lrunB, pb[w], bcast[w], O, b, hh, qw0B, lane, lo, hi);
}

extern "C" void kernel_launch(void* const* d_in, const int* in_sizes, int n_in,
                              void* d_out, int out_size, void* d_ws, size_t ws_size,
                              hipStream_t stream) {
  const float* x = (const float*)d_in[0];
  const float* y = (const float*)d_in[1];
  const int* pad = (const int*)d_in[2];
  const int* tmask = (const int*)d_in[3];
  const float* Wq = (const float*)d_in[4];
  const float* Wk = (const float*)d_in[5];
  const float* Wv = (const float*)d_in[6];
  const float* Wp = (const float*)d_in[7];
  const float* bp = (const float*)d_in[8];

  char* ws = (char*)d_ws;
  unsigned short* xbf = (unsigned short*)(ws + OFF_XBF);
  unsigned short* ybf = (unsigned short*)(ws + OFF_YBF);
  unsigned short* wqb = (unsigned short*)(ws + OFF_WQ);
  unsigned short* wkb = (unsigned short*)(ws + OFF_WK);
  unsigned short* wvb = (unsigned short*)(ws + OFF_WV);
  unsigned short* wpb = (unsigned short*)(ws + OFF_WP);
  unsigned short* qws = (unsigned short*)(ws + OFF_QWS);
  unsigned short* kws = (unsigned short*)(ws + OFF_KWS);
  unsigned short* vtw = (unsigned short*)(ws + OFF_VTWS);
  unsigned short* ows = (unsigned short*)(ws + OFF_OWS);
  int* flags = (int*)(ws + OFF_FLAG);

  init_flag<<<1, 1, 0, stream>>>(flags);
  check_mask<<<64, 256, 0, stream>>>(pad, Bsz * Sseq, flags);
  check_mask<<<2048, 256, 0, stream>>>(tmask, Sseq * Sseq, flags);

  cvt_kernel<<<4096, 256, 0, stream>>>(x, xbf, 1048576, 1.f);
  cvt_kernel<<<4096, 256, 0, stream>>>(y, ybf, 1048576, 1.f);
  cvt_kernel<<<512, 256, 0, stream>>>(Wq, wqb, 131072, QSCALE);
  cvt_kernel<<<512, 256, 0, stream>>>(Wk, wkb, 131072, 1.f);
  cvt_kernel<<<512, 256, 0, stream>>>(Wv, wvb, 131072, 1.f);
  cvt_kernel<<<512, 256, 0, stream>>>(Wp, wpb, 131072, 1.f);

  dim3 gg(64, 8);
  gemm_k<0><<<gg, 256, 0, stream>>>(ybf, wqb, qws, nullptr, nullptr);
  gemm_k<1><<<gg, 256, 0, stream>>>(xbf, wkb, kws, nullptr, nullptr);
  gemm_k<2><<<gg, 256, 0, stream>>>(xbf, wvb, vtw, nullptr, nullptr);

  attn_kernel<<<dim3(16, 64), 256, 0, stream>>>(qws, kws, vtw, ows, pad, tmask, flags);

  gemm_k<3><<<gg, 256, 0, stream>>>(ows, wpb, nullptr, (float*)d_out, bp);
}

// Round 5
// 221.757 us; speedup vs baseline: 1.3600x; 1.3600x over previous
//
#include <hip/hip_runtime.h>
#include <hip/hip_bf16.h>
#include <stdint.h>
#include <stddef.h>

// MultiHA: y@Wq^T -> q; x@Wk^T -> k; x@Wv^T -> v; causal softmax attn; @Wp^T + bp
// B=4 S=2048 D=1024 NH=16 HS=64. All GEMM/attn compute in bf16 MFMA, f32 accum.

typedef __attribute__((ext_vector_type(4))) float f32x4;
typedef __attribute__((ext_vector_type(8))) short s16x8;
typedef __attribute__((ext_vector_type(4))) float float4v;
typedef __attribute__((ext_vector_type(2))) unsigned int u32x2;

#define DEV __device__ __forceinline__

constexpr int Bsz = 4, Sseq = 2048, Dm = 1024, NHn = 16, HSn = 64;
// fold 1/sqrt(HS) * log2(e) into Wq so attention softmax runs in exp2 domain
constexpr float QSCALE = 0.125f * 1.4426950408889634f;

// ---- workspace layout (bytes) ----
constexpr size_t SZ_BF_XY = (size_t)Bsz * Sseq * Dm * 2;  // 16 MiB
constexpr size_t SZ_W     = (size_t)Dm * Dm * 2;          // 2 MiB
constexpr size_t OFF_XBF  = 0;
constexpr size_t OFF_YBF  = OFF_XBF + SZ_BF_XY;
constexpr size_t OFF_WQ   = OFF_YBF + SZ_BF_XY;
constexpr size_t OFF_WK   = OFF_WQ + SZ_W;
constexpr size_t OFF_WV   = OFF_WK + SZ_W;
constexpr size_t OFF_WP   = OFF_WV + SZ_W;
constexpr size_t OFF_QWS  = OFF_WP + SZ_W;   // [BH][S][64] bf16
constexpr size_t OFF_KWS  = OFF_QWS + SZ_BF_XY;
constexpr size_t OFF_VTWS = OFF_KWS + SZ_BF_XY; // [BH][64][S] bf16 (V transposed)
constexpr size_t OFF_OWS  = OFF_VTWS + SZ_BF_XY; // attn out [B][S][D] bf16
constexpr size_t OFF_FLAG = OFF_OWS + SZ_BF_XY;

DEV unsigned short f2bf(float f) {
  union { float f; unsigned int u; } v; v.f = f;
  unsigned int r = (v.u + 0x7FFFu + ((v.u >> 16) & 1u)) >> 16;
  return (unsigned short)r;
}

DEV void gll16(const void* g, void* l) {
  __builtin_amdgcn_global_load_lds((const __attribute__((address_space(1))) unsigned int*)g,
                                   (__attribute__((address_space(3))) unsigned int*)l, 16, 0, 0);
}

DEV unsigned int cvtpk(float a, float b) {
  unsigned int r;
  asm("v_cvt_pk_bf16_f32 %0, %1, %2" : "=v"(r) : "v"(a), "v"(b));
  return r;
}

// ---------------- convert fp32 -> bf16 (x8 per thread) ----------------
__global__ void cvt_kernel(const float* __restrict__ src, unsigned short* __restrict__ dst,
                           int n8, float scale) {
  int i = blockIdx.x * blockDim.x + threadIdx.x;
  if (i >= n8) return;
  const float4v* s = (const float4v*)src + (size_t)i * 2;
  float4v a = s[0], b = s[1];
  s16x8 o;
  o[0] = (short)f2bf(a[0] * scale); o[1] = (short)f2bf(a[1] * scale);
  o[2] = (short)f2bf(a[2] * scale); o[3] = (short)f2bf(a[3] * scale);
  o[4] = (short)f2bf(b[0] * scale); o[5] = (short)f2bf(b[1] * scale);
  o[6] = (short)f2bf(b[2] * scale); o[7] = (short)f2bf(b[3] * scale);
  *(s16x8*)(dst + (size_t)i * 8) = o;
}

// ---------------- mask triviality flag ----------------
__global__ void init_flag(int* f) { f[0] = 1; }
__global__ void check_mask(const int* __restrict__ p, int n, int* __restrict__ f) {
  int bad = 0;
  for (int i = blockIdx.x * blockDim.x + threadIdx.x; i < n; i += gridDim.x * blockDim.x)
    bad |= (p[i] == 0);
  if (bad) atomicAnd(f, 0);
}

// ---------------- 128x128 bf16 GEMM, C[m][n] = sum_k A[m][k] * W[n][k] ----------------
// V=0: Q out bf16 [B,NH,S,HS]   V=1: K out, same layout
// V=2: Vt out bf16 [B,NH,HS,S] (LDS-transposed epilogue)
// V=3: fp32 out [M][1024] + bias
template <int V>
__global__ __launch_bounds__(256) void gemm_k(const unsigned short* __restrict__ A,
                                              const unsigned short* __restrict__ W,
                                              unsigned short* __restrict__ outb,
                                              float* __restrict__ outf,
                                              const float* __restrict__ bias) {
  constexpr int K = 1024;
  __shared__ unsigned short sm[17408]; // lA(4096) + lB(4096); V2 transpose uses 128*136
  unsigned short* lA = sm;
  unsigned short* lB = sm + 4096;
  const int tid = threadIdx.x;
  const int w = tid >> 6, lane = tid & 63, lo = lane & 15, hi = lane >> 4;
  const int wm = w >> 1, wn = w & 1;
  const int m0 = blockIdx.x * 128, n0 = blockIdx.y * 128;
  f32x4 acc[4][4] = {};

  for (int k0 = 0; k0 < K; k0 += 32) {
#pragma unroll
    for (int h = 0; h < 2; ++h) {
      int c = w * 64 + h * 256 + lane;
      gll16(A + (size_t)(m0 + (c >> 2)) * K + k0 + (c & 3) * 8, lA + (size_t)(w * 64 + h * 256) * 8);
      gll16(W + (size_t)(n0 + (c >> 2)) * K + k0 + (c & 3) * 8, lB + (size_t)(w * 64 + h * 256) * 8);
    }
    __syncthreads();
    s16x8 af[4], bfr[4];
#pragma unroll
    for (int mi = 0; mi < 4; ++mi) af[mi] = *(const s16x8*)&lA[(wm * 64 + mi * 16 + lo) * 32 + hi * 8];
#pragma unroll
    for (int ni = 0; ni < 4; ++ni) bfr[ni] = *(const s16x8*)&lB[(wn * 64 + ni * 16 + lo) * 32 + hi * 8];
#pragma unroll
    for (int mi = 0; mi < 4; ++mi)
#pragma unroll
      for (int ni = 0; ni < 4; ++ni)
        acc[mi][ni] = __builtin_amdgcn_mfma_f32_16x16x32_bf16(af[mi], bfr[ni], acc[mi][ni], 0, 0, 0);
    __syncthreads();
  }

  if constexpr (V <= 1) {
#pragma unroll
    for (int mi = 0; mi < 4; ++mi)
#pragma unroll
      for (int ni = 0; ni < 4; ++ni)
#pragma unroll
        for (int j = 0; j < 4; ++j) {
          int m = m0 + wm * 64 + mi * 16 + hi * 4 + j;
          int n = n0 + wn * 64 + ni * 16 + lo;
          int b = m >> 11, s = m & 2047, hh = n >> 6, e = n & 63;
          outb[((size_t)(b * NHn + hh) * Sseq + s) * HSn + e] = f2bf(acc[mi][ni][j]);
        }
  } else if constexpr (V == 2) {
    __syncthreads();
#pragma unroll
    for (int mi = 0; mi < 4; ++mi)
#pragma unroll
      for (int ni = 0; ni < 4; ++ni)
#pragma unroll
        for (int j = 0; j < 4; ++j) {
          int ml = wm * 64 + mi * 16 + hi * 4 + j;
          int nl = wn * 64 + ni * 16 + lo;
          sm[(size_t)nl * 136 + ml] = f2bf(acc[mi][ni][j]);
        }
    __syncthreads();
    int nl = tid >> 1, half = tid & 1;
    int b = m0 >> 11, hh = (n0 + nl) >> 6, e = (n0 + nl) & 63;
    unsigned short* dst = outb + ((size_t)(b * NHn + hh) * HSn + e) * Sseq + (m0 & 2047) + half * 64;
#pragma unroll
    for (int i = 0; i < 8; ++i)
      *(s16x8*)(dst + i * 8) = *(const s16x8*)&sm[(size_t)nl * 136 + half * 64 + i * 8];
  } else {
    float bv[4];
#pragma unroll
    for (int ni = 0; ni < 4; ++ni) bv[ni] = bias[n0 + wn * 64 + ni * 16 + lo];
#pragma unroll
    for (int mi = 0; mi < 4; ++mi)
#pragma unroll
      for (int ni = 0; ni < 4; ++ni)
#pragma unroll
        for (int j = 0; j < 4; ++j) {
          int m = m0 + wm * 64 + mi * 16 + hi * 4 + j;
          int n = n0 + wn * 64 + ni * 16 + lo;
          outf[(size_t)m * 1024 + n] = acc[mi][ni][j] + bv[ni];
        }
  }
}

// ---------------- flash attention (R3 structure, swapped-QK^T softmax) ----------------
// Block (ip, bh): q-tiles qtA=ip, qtB=15-ip (128 rows each); 34 K-tile iterations
// per block; double-buffered K/V with issue-early/write-late register staging.
// Swapped QK^T: st[mq][t][j] = S[kpos=k0+t*16+hi*4+j][q=qw0+mq*16+lo] -> softmax
// reduction is lane-local over {t,j} + 2 shuffles across hi; alpha/l lane-local.
// P packed to pb[q][kpos] via cvt_pk b64 writes; PV identical to R3:
// oacc[et][ql][j] = O^T[e=et*16+hi*4+j][q=qw0+ql*16+lo].
DEV void attn_tile32(const unsigned short* __restrict__ kbc,
                     const unsigned short* __restrict__ vbc,
                     const s16x8 (&qf)[2][2], f32x4 (&oacc)[4][2],
                     float (&mrun)[2], float (&lrun)[2],
                     unsigned short* __restrict__ pbw,
                     int k0, int qw0, int lo, int hi, int b,
                     const int* __restrict__ pad, const int* __restrict__ tmask,
                     bool trivial) {
  if (k0 > qw0 + 31) return; // wave-uniform: tile entirely above the diagonal

  // S^T = K Q^T (operand-swapped; fragment loads identical to R3)
  f32x4 st[2][4];
#pragma unroll
  for (int t = 0; t < 4; ++t) {
    f32x4 z0 = {0.f, 0.f, 0.f, 0.f}, z1 = {0.f, 0.f, 0.f, 0.f};
#pragma unroll
    for (int kk = 0; kk < 2; ++kk) {
      s16x8 kfr = *(const s16x8*)&kbc[(t * 16 + lo) * 72 + kk * 32 + hi * 8];
      z0 = __builtin_amdgcn_mfma_f32_16x16x32_bf16(kfr, qf[0][kk], z0, 0, 0, 0);
      z1 = __builtin_amdgcn_mfma_f32_16x16x32_bf16(kfr, qf[1][kk], z1, 0, 0, 0);
    }
    st[0][t] = z0; st[1][t] = z1;
  }
  if (k0 + 63 > qw0) { // diagonal tiles: causal mask (kpos > q)
#pragma unroll
    for (int mq = 0; mq < 2; ++mq) {
      int qg = qw0 + mq * 16 + lo;
#pragma unroll
      for (int t = 0; t < 4; ++t)
#pragma unroll
        for (int j = 0; j < 4; ++j)
          if (k0 + t * 16 + hi * 4 + j > qg) st[mq][t][j] = -3e38f;
    }
  }
  if (!trivial) { // general pad/time masks (not hit for all-ones inputs)
#pragma unroll
    for (int t = 0; t < 4; ++t)
#pragma unroll
      for (int j = 0; j < 4; ++j) {
        int kg = k0 + t * 16 + hi * 4 + j;
        int pv = pad[b * Sseq + kg];
#pragma unroll
        for (int mq = 0; mq < 2; ++mq) {
          int qg = qw0 + mq * 16 + lo;
          if (!pv || !tmask[(size_t)qg * Sseq + kg]) st[mq][t][j] = -3e38f;
        }
      }
  }
  // online softmax per q-column (lane-local + 2 shuffles over hi-groups)
#pragma unroll
  for (int mq = 0; mq < 2; ++mq) {
    float m0v = fmaxf(fmaxf(st[mq][0][0], st[mq][0][1]), fmaxf(st[mq][0][2], st[mq][0][3]));
    float m1v = fmaxf(fmaxf(st[mq][1][0], st[mq][1][1]), fmaxf(st[mq][1][2], st[mq][1][3]));
    float m2v = fmaxf(fmaxf(st[mq][2][0], st[mq][2][1]), fmaxf(st[mq][2][2], st[mq][2][3]));
    float m3v = fmaxf(fmaxf(st[mq][3][0], st[mq][3][1]), fmaxf(st[mq][3][2], st[mq][3][3]));
    float mx = fmaxf(fmaxf(m0v, m1v), fmaxf(m2v, m3v));
    mx = fmaxf(mx, __shfl_xor(mx, 16, 64));
    mx = fmaxf(mx, __shfl_xor(mx, 32, 64));
    const float mnew = fmaxf(mrun[mq], mx);
    const float al = __builtin_amdgcn_exp2f(mrun[mq] - mnew);
    mrun[mq] = mnew;
    float r0 = 0.f, r1 = 0.f, r2 = 0.f, r3 = 0.f;
#pragma unroll
    for (int j = 0; j < 4; ++j) {
      float p0 = __builtin_amdgcn_exp2f(st[mq][0][j] - mnew); st[mq][0][j] = p0; r0 += p0;
      float p1 = __builtin_amdgcn_exp2f(st[mq][1][j] - mnew); st[mq][1][j] = p1; r1 += p1;
      float p2 = __builtin_amdgcn_exp2f(st[mq][2][j] - mnew); st[mq][2][j] = p2; r2 += p2;
      float p3 = __builtin_amdgcn_exp2f(st[mq][3][j] - mnew); st[mq][3][j] = p3; r3 += p3;
    }
    float rs = (r0 + r1) + (r2 + r3);
    rs += __shfl_xor(rs, 16, 64);
    rs += __shfl_xor(rs, 32, 64);
    lrun[mq] = lrun[mq] * al + rs;
    // rescale this column's accumulators (lane-local alpha)
#pragma unroll
    for (int et = 0; et < 4; ++et) oacc[et][mq] *= al;
    // pack P column segment -> pb[q][kpos] (b64 writes, 4 kpos each)
#pragma unroll
    for (int t = 0; t < 4; ++t) {
      u32x2 dd = {cvtpk(st[mq][t][0], st[mq][t][1]), cvtpk(st[mq][t][2], st[mq][t][3])};
      *(u32x2*)&pbw[(mq * 16 + lo) * 72 + t * 16 + hi * 4] = dd;
    }
  }
  // O^T += V^T P^T  (identical to R3)
  s16x8 pf[2][2];
#pragma unroll
  for (int ql = 0; ql < 2; ++ql)
#pragma unroll
    for (int kk = 0; kk < 2; ++kk)
      pf[ql][kk] = *(const s16x8*)&pbw[(ql * 16 + lo) * 72 + kk * 32 + hi * 8];
#pragma unroll
  for (int et = 0; et < 4; ++et)
#pragma unroll
    for (int kk = 0; kk < 2; ++kk) {
      s16x8 vfr = *(const s16x8*)&vbc[(et * 16 + lo) * 72 + kk * 32 + hi * 8];
      oacc[et][0] = __builtin_amdgcn_mfma_f32_16x16x32_bf16(vfr, pf[0][kk], oacc[et][0], 0, 0, 0);
      oacc[et][1] = __builtin_amdgcn_mfma_f32_16x16x32_bf16(vfr, pf[1][kk], oacc[et][1], 0, 0, 0);
    }
}

// normalize by l (lane-local) and write O via per-wave LDS transpose
DEV void attn_epilogue32(f32x4 (&oacc)[4][2], float (&lrun)[2],
                         unsigned short* __restrict__ pbw,
                         unsigned short* __restrict__ O, int b, int hh, int qw0,
                         int lane, int lo, int hi) {
  const float inv0 = 1.f / lrun[0];
  const float inv1 = 1.f / lrun[1];
#pragma unroll
  for (int et = 0; et < 4; ++et) {
    f32x4 o0 = oacc[et][0] * inv0;
    f32x4 o1 = oacc[et][1] * inv1;
    u32x2 d0 = {cvtpk(o0[0], o0[1]), cvtpk(o0[2], o0[3])};
    u32x2 d1 = {cvtpk(o1[0], o1[1]), cvtpk(o1[2], o1[3])};
    *(u32x2*)&pbw[(0 * 16 + lo) * 72 + et * 16 + hi * 4] = d0;
    *(u32x2*)&pbw[(1 * 16 + lo) * 72 + et * 16 + hi * 4] = d1;
  }
  int q = lane & 31, half = lane >> 5;
  unsigned short* dst = O + ((size_t)b * Sseq + qw0 + q) * Dm + hh * HSn + half * 32;
#pragma unroll
  for (int i = 0; i < 4; ++i)
    *(s16x8*)(dst + i * 8) = *(const s16x8*)&pbw[q * 72 + half * 32 + i * 8];
}

__global__ __launch_bounds__(256, 2) void attn_kernel(const unsigned short* __restrict__ Q,
                                                      const unsigned short* __restrict__ Kg,
                                                      const unsigned short* __restrict__ Vt,
                                                      unsigned short* __restrict__ O,
                                                      const int* __restrict__ pad,
                                                      const int* __restrict__ tmask,
                                                      const int* __restrict__ flags) {
  __shared__ unsigned short kb[2][64 * 72];  // 18.0 KiB
  __shared__ unsigned short vb[2][64 * 72];  // 18.0 KiB
  __shared__ unsigned short pb[4][32 * 72];  // 18.0 KiB (wave-private P scratch)

  const int ip = blockIdx.x, bh = blockIdx.y;
  const int b = bh >> 4, hh = bh & 15;
  const int tid = threadIdx.x, w = tid >> 6, lane = tid & 63, lo = lane & 15, hi = lane >> 4;
  const int qtA = ip, qtB = 15 - ip;
  const int qw0A = qtA * 128 + w * 32, qw0B = qtB * 128 + w * 32;
  const int ktA = 2 * qtA + 1;       // last K-tile index tile A needs
  const int ktmax = 2 * qtB + 2;     // number of K-tiles tile B needs
  const bool trivial = flags[0] != 0;

  const unsigned short* Qb = Q + (size_t)bh * Sseq * HSn;
  const unsigned short* Kb = Kg + (size_t)bh * Sseq * HSn;
  const unsigned short* Vb = Vt + (size_t)bh * HSn * Sseq;

  // Q fragments (B-operand of swapped QK^T: col=q=lo-row of fragment, k=kk*32+hi*8+e)
  s16x8 qfA[2][2], qfB[2][2];
#pragma unroll
  for (int mq = 0; mq < 2; ++mq)
#pragma unroll
    for (int kk = 0; kk < 2; ++kk) {
      qfA[mq][kk] = *(const s16x8*)&Qb[(size_t)(qw0A + mq * 16 + lo) * HSn + kk * 32 + hi * 8];
      qfB[mq][kk] = *(const s16x8*)&Qb[(size_t)(qw0B + mq * 16 + lo) * HSn + kk * 32 + hi * 8];
    }

  f32x4 oaccA[4][2] = {}, oaccB[4][2] = {};
  float mrunA[2] = {-3e38f, -3e38f}, lrunA[2] = {0.f, 0.f};
  float mrunB[2] = {-3e38f, -3e38f}, lrunB[2] = {0.f, 0.f};

  const int sr = tid >> 2, sc = (tid & 3) * 16;

  // prologue: stage kt=0 into buffer 0
  s16x8 rk0, rk1, rv0, rv1;
  {
    const unsigned short* gk = Kb + (size_t)sr * HSn + sc;
    rk0 = *(const s16x8*)gk; rk1 = *(const s16x8*)(gk + 8);
    const unsigned short* gv = Vb + (size_t)sr * Sseq + sc;
    rv0 = *(const s16x8*)gv; rv1 = *(const s16x8*)(gv + 8);
  }
  *(s16x8*)&kb[0][sr * 72 + sc] = rk0; *(s16x8*)&kb[0][sr * 72 + sc + 8] = rk1;
  *(s16x8*)&vb[0][sr * 72 + sc] = rv0; *(s16x8*)&vb[0][sr * 72 + sc + 8] = rv1;
  __syncthreads();

  for (int kt = 0; kt < ktmax; ++kt) {
    const int cur = kt & 1, k0 = kt * 64;
    const bool pre = (kt + 1 < ktmax);
    if (pre) { // issue next-tile loads early; latency hides under compute
      const int k1 = k0 + 64;
      const unsigned short* gk = Kb + (size_t)(k1 + sr) * HSn + sc;
      rk0 = *(const s16x8*)gk; rk1 = *(const s16x8*)(gk + 8);
      const unsigned short* gv = Vb + (size_t)sr * Sseq + k1 + sc;
      rv0 = *(const s16x8*)gv; rv1 = *(const s16x8*)(gv + 8);
    }
    const unsigned short* kbc = kb[cur];
    const unsigned short* vbc = vb[cur];
    if (kt <= ktA)
      attn_tile32(kbc, vbc, qfA, oaccA, mrunA, lrunA, pb[w],
                  k0, qw0A, lo, hi, b, pad, tmask, trivial);
    attn_tile32(kbc, vbc, qfB, oaccB, mrunB, lrunB, pb[w],
                k0, qw0B, lo, hi, b, pad, tmask, trivial);
    if (pre) { // write-late into the other buffer
      const int nb = cur ^ 1;
      *(s16x8*)&kb[nb][sr * 72 + sc] = rk0; *(s16x8*)&kb[nb][sr * 72 + sc + 8] = rk1;
      *(s16x8*)&vb[nb][sr * 72 + sc] = rv0; *(s16x8*)&vb[nb][sr * 72 + sc + 8] = rv1;
    }
    __syncthreads();
  }

  attn_epilogue32(oaccA, lrunA, pb[w], O, b, hh, qw0A, lane, lo, hi);
  attn_epilogue32(oaccB, lrunB, pb[w], O, b, hh, qw0B, lane, lo, hi);
}

extern "C" void kernel_launch(void* const* d_in, const int* in_sizes, int n_in,
                              void* d_out, int out_size, void* d_ws, size_t ws_size,
                              hipStream_t stream) {
  const float* x = (const float*)d_in[0];
  const float* y = (const float*)d_in[1];
  const int* pad = (const int*)d_in[2];
  const int* tmask = (const int*)d_in[3];
  const float* Wq = (const float*)d_in[4];
  const float* Wk = (const float*)d_in[5];
  const float* Wv = (const float*)d_in[6];
  const float* Wp = (const float*)d_in[7];
  const float* bp = (const float*)d_in[8];

  char* ws = (char*)d_ws;
  unsigned short* xbf = (unsigned short*)(ws + OFF_XBF);
  unsigned short* ybf = (unsigned short*)(ws + OFF_YBF);
  unsigned short* wqb = (unsigned short*)(ws + OFF_WQ);
  unsigned short* wkb = (unsigned short*)(ws + OFF_WK);
  unsigned short* wvb = (unsigned short*)(ws + OFF_WV);
  unsigned short* wpb = (unsigned short*)(ws + OFF_WP);
  unsigned short* qws = (unsigned short*)(ws + OFF_QWS);
  unsigned short* kws = (unsigned short*)(ws + OFF_KWS);
  unsigned short* vtw = (unsigned short*)(ws + OFF_VTWS);
  unsigned short* ows = (unsigned short*)(ws + OFF_OWS);
  int* flags = (int*)(ws + OFF_FLAG);

  init_flag<<<1, 1, 0, stream>>>(flags);
  check_mask<<<64, 256, 0, stream>>>(pad, Bsz * Sseq, flags);
  check_mask<<<2048, 256, 0, stream>>>(tmask, Sseq * Sseq, flags);

  cvt_kernel<<<4096, 256, 0, stream>>>(x, xbf, 1048576, 1.f);
  cvt_kernel<<<4096, 256, 0, stream>>>(y, ybf, 1048576, 1.f);
  cvt_kernel<<<512, 256, 0, stream>>>(Wq, wqb, 131072, QSCALE);
  cvt_kernel<<<512, 256, 0, stream>>>(Wk, wkb, 131072, 1.f);
  cvt_kernel<<<512, 256, 0, stream>>>(Wv, wvb, 131072, 1.f);
  cvt_kernel<<<512, 256, 0, stream>>>(Wp, wpb, 131072, 1.f);

  dim3 gg(64, 8);
  gemm_k<0><<<gg, 256, 0, stream>>>(ybf, wqb, qws, nullptr, nullptr);
  gemm_k<1><<<gg, 256, 0, stream>>>(xbf, wkb, kws, nullptr, nullptr);
  gemm_k<2><<<gg, 256, 0, stream>>>(xbf, wvb, vtw, nullptr, nullptr);

  attn_kernel<<<dim3(8, 64), 256, 0, stream>>>(qws, kws, vtw, ows, pad, tmask, flags);

  gemm_k<3><<<gg, 256, 0, stream>>>(ows, wpb, nullptr, (float*)d_out, bp);
}

// Round 6
// 216.065 us; speedup vs baseline: 1.3958x; 1.0263x over previous
//
#include <hip/hip_runtime.h>
#include <hip/hip_bf16.h>
#include <stdint.h>
#include <stddef.h>

// MultiHA: y@Wq^T -> q; x@Wk^T -> k; x@Wv^T -> v; causal softmax attn; @Wp^T + bp
// B=4 S=2048 D=1024 NH=16 HS=64. All GEMM/attn compute in bf16 MFMA, f32 accum.

typedef __attribute__((ext_vector_type(4))) float f32x4;
typedef __attribute__((ext_vector_type(8))) short s16x8;
typedef __attribute__((ext_vector_type(4))) float float4v;
typedef __attribute__((ext_vector_type(2))) unsigned int u32x2;

#define DEV __device__ __forceinline__

constexpr int Bsz = 4, Sseq = 2048, Dm = 1024, NHn = 16, HSn = 64;
// fold 1/sqrt(HS) * log2(e) into Wq so attention softmax runs in exp2 domain
constexpr float QSCALE = 0.125f * 1.4426950408889634f;

// ---- workspace layout (bytes) ----
constexpr size_t SZ_BF_XY = (size_t)Bsz * Sseq * Dm * 2;  // 16 MiB
constexpr size_t SZ_W     = (size_t)Dm * Dm * 2;          // 2 MiB
constexpr size_t OFF_XBF  = 0;
constexpr size_t OFF_YBF  = OFF_XBF + SZ_BF_XY;
constexpr size_t OFF_WQ   = OFF_YBF + SZ_BF_XY;
constexpr size_t OFF_WK   = OFF_WQ + SZ_W;
constexpr size_t OFF_WV   = OFF_WK + SZ_W;
constexpr size_t OFF_WP   = OFF_WV + SZ_W;
constexpr size_t OFF_QWS  = OFF_WP + SZ_W;   // [BH][S][64] bf16
constexpr size_t OFF_KWS  = OFF_QWS + SZ_BF_XY;
constexpr size_t OFF_VTWS = OFF_KWS + SZ_BF_XY; // [BH][64][S] bf16 (V transposed)
constexpr size_t OFF_OWS  = OFF_VTWS + SZ_BF_XY; // attn out [B][S][D] bf16
constexpr size_t OFF_FLAG = OFF_OWS + SZ_BF_XY;

DEV unsigned short f2bf(float f) {
  union { float f; unsigned int u; } v; v.f = f;
  unsigned int r = (v.u + 0x7FFFu + ((v.u >> 16) & 1u)) >> 16;
  return (unsigned short)r;
}

DEV void gll16(const void* g, void* l) {
  __builtin_amdgcn_global_load_lds((const __attribute__((address_space(1))) unsigned int*)g,
                                   (__attribute__((address_space(3))) unsigned int*)l, 16, 0, 0);
}

DEV unsigned int cvtpk(float a, float b) {
  unsigned int r;
  asm("v_cvt_pk_bf16_f32 %0, %1, %2" : "=v"(r) : "v"(a), "v"(b));
  return r;
}

// ---------------- fused fp32 -> bf16 conversion of all inputs ----------------
// blocks 0..4095: x, 4096..8191: y, then 512-block chunks: Wq(QSCALE), Wk, Wv, Wp
__global__ void cvt_all(const float* __restrict__ x, const float* __restrict__ y,
                        const float* __restrict__ Wq, const float* __restrict__ Wk,
                        const float* __restrict__ Wv, const float* __restrict__ Wp,
                        char* __restrict__ ws) {
  const int blk = blockIdx.x;
  const float* src;
  unsigned short* dst;
  int b8;
  float scale = 1.f;
  if (blk < 4096)      { src = x;  dst = (unsigned short*)(ws + OFF_XBF); b8 = blk; }
  else if (blk < 8192) { src = y;  dst = (unsigned short*)(ws + OFF_YBF); b8 = blk - 4096; }
  else if (blk < 8704) { src = Wq; dst = (unsigned short*)(ws + OFF_WQ);  b8 = blk - 8192; scale = QSCALE; }
  else if (blk < 9216) { src = Wk; dst = (unsigned short*)(ws + OFF_WK);  b8 = blk - 8704; }
  else if (blk < 9728) { src = Wv; dst = (unsigned short*)(ws + OFF_WV);  b8 = blk - 9216; }
  else                 { src = Wp; dst = (unsigned short*)(ws + OFF_WP);  b8 = blk - 9728; }
  const size_t i = (size_t)b8 * 256 + threadIdx.x;
  const float4v* s = (const float4v*)src + i * 2;
  float4v a = s[0], b = s[1];
  s16x8 o;
  o[0] = (short)f2bf(a[0] * scale); o[1] = (short)f2bf(a[1] * scale);
  o[2] = (short)f2bf(a[2] * scale); o[3] = (short)f2bf(a[3] * scale);
  o[4] = (short)f2bf(b[0] * scale); o[5] = (short)f2bf(b[1] * scale);
  o[6] = (short)f2bf(b[2] * scale); o[7] = (short)f2bf(b[3] * scale);
  *(s16x8*)(dst + i * 8) = o;
}

// ---------------- mask triviality flag ----------------
__global__ void init_flag(int* f) { f[0] = 1; }
__global__ void check_mask(const int* __restrict__ p, int n, int* __restrict__ f) {
  int bad = 0;
  for (int i = blockIdx.x * blockDim.x + threadIdx.x; i < n; i += gridDim.x * blockDim.x)
    bad |= (p[i] == 0);
  if (bad) atomicAnd(f, 0);
}

// ---------------- GEMM main-loop body (128x128 tile, C[m][n] = sum_k A[m][k]*W[n][k]) ----
DEV void gemm_core(const unsigned short* __restrict__ A, const unsigned short* __restrict__ W,
                   unsigned short* __restrict__ lA, unsigned short* __restrict__ lB,
                   f32x4 (&acc)[4][4], int m0, int n0, int w, int lane, int lo, int hi,
                   int wm, int wn) {
  constexpr int K = 1024;
  for (int k0 = 0; k0 < K; k0 += 32) {
#pragma unroll
    for (int h = 0; h < 2; ++h) {
      int c = w * 64 + h * 256 + lane;
      gll16(A + (size_t)(m0 + (c >> 2)) * K + k0 + (c & 3) * 8, lA + (size_t)(w * 64 + h * 256) * 8);
      gll16(W + (size_t)(n0 + (c >> 2)) * K + k0 + (c & 3) * 8, lB + (size_t)(w * 64 + h * 256) * 8);
    }
    __syncthreads();
    s16x8 af[4], bfr[4];
#pragma unroll
    for (int mi = 0; mi < 4; ++mi) af[mi] = *(const s16x8*)&lA[(wm * 64 + mi * 16 + lo) * 32 + hi * 8];
#pragma unroll
    for (int ni = 0; ni < 4; ++ni) bfr[ni] = *(const s16x8*)&lB[(wn * 64 + ni * 16 + lo) * 32 + hi * 8];
#pragma unroll
    for (int mi = 0; mi < 4; ++mi)
#pragma unroll
      for (int ni = 0; ni < 4; ++ni)
        acc[mi][ni] = __builtin_amdgcn_mfma_f32_16x16x32_bf16(af[mi], bfr[ni], acc[mi][ni], 0, 0, 0);
    __syncthreads();
  }
}

// ---------------- fused QKV projection GEMM (grid z: 0=Q, 1=K, 2=V-transposed) ----------
__global__ __launch_bounds__(256) void qkv_gemm(const unsigned short* __restrict__ xbf,
                                                const unsigned short* __restrict__ ybf,
                                                const unsigned short* __restrict__ wqb,
                                                const unsigned short* __restrict__ wkb,
                                                const unsigned short* __restrict__ wvb,
                                                unsigned short* __restrict__ qws,
                                                unsigned short* __restrict__ kws,
                                                unsigned short* __restrict__ vtw) {
  __shared__ unsigned short sm[17408]; // lA(4096) + lB(4096); V-transpose uses 128*136
  unsigned short* lA = sm;
  unsigned short* lB = sm + 4096;
  const int tid = threadIdx.x;
  const int w = tid >> 6, lane = tid & 63, lo = lane & 15, hi = lane >> 4;
  const int wm = w >> 1, wn = w & 1;
  const int m0 = blockIdx.x * 128, n0 = blockIdx.y * 128;
  const int z = blockIdx.z;
  const unsigned short* A = (z == 0) ? ybf : xbf;
  const unsigned short* W = (z == 0) ? wqb : ((z == 1) ? wkb : wvb);
  f32x4 acc[4][4] = {};
  gemm_core(A, W, lA, lB, acc, m0, n0, w, lane, lo, hi, wm, wn);

  if (z <= 1) { // Q / K: bf16 [B,NH,S,HS]
    unsigned short* outb = (z == 0) ? qws : kws;
#pragma unroll
    for (int mi = 0; mi < 4; ++mi)
#pragma unroll
      for (int ni = 0; ni < 4; ++ni)
#pragma unroll
        for (int j = 0; j < 4; ++j) {
          int m = m0 + wm * 64 + mi * 16 + hi * 4 + j;
          int n = n0 + wn * 64 + ni * 16 + lo;
          int b = m >> 11, s = m & 2047, hh = n >> 6, e = n & 63;
          outb[((size_t)(b * NHn + hh) * Sseq + s) * HSn + e] = f2bf(acc[mi][ni][j]);
        }
  } else { // V: bf16 [B,NH,HS,S] via LDS transpose
    __syncthreads();
#pragma unroll
    for (int mi = 0; mi < 4; ++mi)
#pragma unroll
      for (int ni = 0; ni < 4; ++ni)
#pragma unroll
        for (int j = 0; j < 4; ++j) {
          int ml = wm * 64 + mi * 16 + hi * 4 + j;
          int nl = wn * 64 + ni * 16 + lo;
          sm[(size_t)nl * 136 + ml] = f2bf(acc[mi][ni][j]);
        }
    __syncthreads();
    int nl = tid >> 1, half = tid & 1;
    int b = m0 >> 11, hh = (n0 + nl) >> 6, e = (n0 + nl) & 63;
    unsigned short* dst = vtw + ((size_t)(b * NHn + hh) * HSn + e) * Sseq + (m0 & 2047) + half * 64;
#pragma unroll
    for (int i = 0; i < 8; ++i)
      *(s16x8*)(dst + i * 8) = *(const s16x8*)&sm[(size_t)nl * 136 + half * 64 + i * 8];
  }
}

// ---------------- final projection GEMM: fp32 out [M][1024] + bias ----------------
__global__ __launch_bounds__(256) void gemm_p(const unsigned short* __restrict__ A,
                                              const unsigned short* __restrict__ W,
                                              float* __restrict__ outf,
                                              const float* __restrict__ bias) {
  __shared__ unsigned short sm[8192];
  unsigned short* lA = sm;
  unsigned short* lB = sm + 4096;
  const int tid = threadIdx.x;
  const int w = tid >> 6, lane = tid & 63, lo = lane & 15, hi = lane >> 4;
  const int wm = w >> 1, wn = w & 1;
  const int m0 = blockIdx.x * 128, n0 = blockIdx.y * 128;
  f32x4 acc[4][4] = {};
  gemm_core(A, W, lA, lB, acc, m0, n0, w, lane, lo, hi, wm, wn);
  float bv[4];
#pragma unroll
  for (int ni = 0; ni < 4; ++ni) bv[ni] = bias[n0 + wn * 64 + ni * 16 + lo];
#pragma unroll
  for (int mi = 0; mi < 4; ++mi)
#pragma unroll
    for (int ni = 0; ni < 4; ++ni)
#pragma unroll
      for (int j = 0; j < 4; ++j) {
        int m = m0 + wm * 64 + mi * 16 + hi * 4 + j;
        int n = n0 + wn * 64 + ni * 16 + lo;
        outf[(size_t)m * 1024 + n] = acc[mi][ni][j] + bv[ni];
      }
}

// ---------------- flash attention (swapped-QK^T, shared K/V fragments, split P) --------
// Block (ip, bh): q-tiles qtA=ip, qtB=15-ip (128 rows each); 34 K-tile iterations
// per block; double-buffered K/V with issue-early/write-late register staging.
// K/V fragments are loaded ONCE per iteration and shared by both tile calls;
// A and B have separate P scratch -> the two chains are independent (ILP).
// st[mq][t][j] = S[kpos=k0+t*16+hi*4+j][q=qw0+mq*16+lo];
// oacc[et][ql][j] = O^T[e=et*16+hi*4+j][q=qw0+ql*16+lo].
DEV void attn_tile32(const s16x8 (&kfr)[4][2], const s16x8 (&vfr)[4][2],
                     const s16x8 (&qf)[2][2], f32x4 (&oacc)[4][2],
                     float (&mrun)[2], float (&lrun)[2],
                     unsigned short* __restrict__ pbw,
                     int k0, int qw0, int lo, int hi, int b,
                     const int* __restrict__ pad, const int* __restrict__ tmask,
                     bool trivial) {
  if (k0 > qw0 + 31) return; // wave-uniform: tile entirely above the diagonal

  // S^T = K Q^T (operand-swapped)
  f32x4 st[2][4];
#pragma unroll
  for (int t = 0; t < 4; ++t) {
    f32x4 z0 = {0.f, 0.f, 0.f, 0.f}, z1 = {0.f, 0.f, 0.f, 0.f};
#pragma unroll
    for (int kk = 0; kk < 2; ++kk) {
      z0 = __builtin_amdgcn_mfma_f32_16x16x32_bf16(kfr[t][kk], qf[0][kk], z0, 0, 0, 0);
      z1 = __builtin_amdgcn_mfma_f32_16x16x32_bf16(kfr[t][kk], qf[1][kk], z1, 0, 0, 0);
    }
    st[0][t] = z0; st[1][t] = z1;
  }
  if (k0 + 63 > qw0) { // diagonal tiles: causal mask (kpos > q)
#pragma unroll
    for (int mq = 0; mq < 2; ++mq) {
      int qg = qw0 + mq * 16 + lo;
#pragma unroll
      for (int t = 0; t < 4; ++t)
#pragma unroll
        for (int j = 0; j < 4; ++j)
          if (k0 + t * 16 + hi * 4 + j > qg) st[mq][t][j] = -3e38f;
    }
  }
  if (!trivial) { // general pad/time masks (not hit for all-ones inputs)
#pragma unroll
    for (int t = 0; t < 4; ++t)
#pragma unroll
      for (int j = 0; j < 4; ++j) {
        int kg = k0 + t * 16 + hi * 4 + j;
        int pv = pad[b * Sseq + kg];
#pragma unroll
        for (int mq = 0; mq < 2; ++mq) {
          int qg = qw0 + mq * 16 + lo;
          if (!pv || !tmask[(size_t)qg * Sseq + kg]) st[mq][t][j] = -3e38f;
        }
      }
  }
  // online softmax per q-column (lane-local + 2 shuffles over hi-groups)
#pragma unroll
  for (int mq = 0; mq < 2; ++mq) {
    float m0v = fmaxf(fmaxf(st[mq][0][0], st[mq][0][1]), fmaxf(st[mq][0][2], st[mq][0][3]));
    float m1v = fmaxf(fmaxf(st[mq][1][0], st[mq][1][1]), fmaxf(st[mq][1][2], st[mq][1][3]));
    float m2v = fmaxf(fmaxf(st[mq][2][0], st[mq][2][1]), fmaxf(st[mq][2][2], st[mq][2][3]));
    float m3v = fmaxf(fmaxf(st[mq][3][0], st[mq][3][1]), fmaxf(st[mq][3][2], st[mq][3][3]));
    float mx = fmaxf(fmaxf(m0v, m1v), fmaxf(m2v, m3v));
    mx = fmaxf(mx, __shfl_xor(mx, 16, 64));
    mx = fmaxf(mx, __shfl_xor(mx, 32, 64));
    const float mnew = fmaxf(mrun[mq], mx);
    const float al = __builtin_amdgcn_exp2f(mrun[mq] - mnew);
    mrun[mq] = mnew;
    float r0 = 0.f, r1 = 0.f, r2 = 0.f, r3 = 0.f;
#pragma unroll
    for (int j = 0; j < 4; ++j) {
      float p0 = __builtin_amdgcn_exp2f(st[mq][0][j] - mnew); st[mq][0][j] = p0; r0 += p0;
      float p1 = __builtin_amdgcn_exp2f(st[mq][1][j] - mnew); st[mq][1][j] = p1; r1 += p1;
      float p2 = __builtin_amdgcn_exp2f(st[mq][2][j] - mnew); st[mq][2][j] = p2; r2 += p2;
      float p3 = __builtin_amdgcn_exp2f(st[mq][3][j] - mnew); st[mq][3][j] = p3; r3 += p3;
    }
    float rs = (r0 + r1) + (r2 + r3);
    rs += __shfl_xor(rs, 16, 64);
    rs += __shfl_xor(rs, 32, 64);
    lrun[mq] = lrun[mq] * al + rs;
    // rescale this column's accumulators (lane-local alpha)
#pragma unroll
    for (int et = 0; et < 4; ++et) oacc[et][mq] *= al;
    // pack P column segment -> pb[q][kpos] (b64 writes, 4 kpos each)
#pragma unroll
    for (int t = 0; t < 4; ++t) {
      u32x2 dd = {cvtpk(st[mq][t][0], st[mq][t][1]), cvtpk(st[mq][t][2], st[mq][t][3])};
      *(u32x2*)&pbw[(mq * 16 + lo) * 72 + t * 16 + hi * 4] = dd;
    }
  }
  // O^T += V^T P^T
  s16x8 pf[2][2];
#pragma unroll
  for (int ql = 0; ql < 2; ++ql)
#pragma unroll
    for (int kk = 0; kk < 2; ++kk)
      pf[ql][kk] = *(const s16x8*)&pbw[(ql * 16 + lo) * 72 + kk * 32 + hi * 8];
#pragma unroll
  for (int et = 0; et < 4; ++et)
#pragma unroll
    for (int kk = 0; kk < 2; ++kk) {
      oacc[et][0] = __builtin_amdgcn_mfma_f32_16x16x32_bf16(vfr[et][kk], pf[0][kk], oacc[et][0], 0, 0, 0);
      oacc[et][1] = __builtin_amdgcn_mfma_f32_16x16x32_bf16(vfr[et][kk], pf[1][kk], oacc[et][1], 0, 0, 0);
    }
}

// normalize by l (lane-local) and write O via per-wave LDS transpose
DEV void attn_epilogue32(f32x4 (&oacc)[4][2], float (&lrun)[2],
                         unsigned short* __restrict__ pbw,
                         unsigned short* __restrict__ O, int b, int hh, int qw0,
                         int lane, int lo, int hi) {
  const float inv0 = 1.f / lrun[0];
  const float inv1 = 1.f / lrun[1];
#pragma unroll
  for (int et = 0; et < 4; ++et) {
    f32x4 o0 = oacc[et][0] * inv0;
    f32x4 o1 = oacc[et][1] * inv1;
    u32x2 d0 = {cvtpk(o0[0], o0[1]), cvtpk(o0[2], o0[3])};
    u32x2 d1 = {cvtpk(o1[0], o1[1]), cvtpk(o1[2], o1[3])};
    *(u32x2*)&pbw[(0 * 16 + lo) * 72 + et * 16 + hi * 4] = d0;
    *(u32x2*)&pbw[(1 * 16 + lo) * 72 + et * 16 + hi * 4] = d1;
  }
  int q = lane & 31, half = lane >> 5;
  unsigned short* dst = O + ((size_t)b * Sseq + qw0 + q) * Dm + hh * HSn + half * 32;
#pragma unroll
  for (int i = 0; i < 4; ++i)
    *(s16x8*)(dst + i * 8) = *(const s16x8*)&pbw[q * 72 + half * 32 + i * 8];
}

__global__ __launch_bounds__(256, 2) void attn_kernel(const unsigned short* __restrict__ Q,
                                                      const unsigned short* __restrict__ Kg,
                                                      const unsigned short* __restrict__ Vt,
                                                      unsigned short* __restrict__ O,
                                                      const int* __restrict__ pad,
                                                      const int* __restrict__ tmask,
                                                      const int* __restrict__ flags) {
  __shared__ unsigned short kb[2][64 * 72];     // 18.0 KiB
  __shared__ unsigned short vb[2][64 * 72];     // 18.0 KiB
  __shared__ unsigned short pb[4][2][32 * 72];  // 36.0 KiB (per-wave, A/B separate)

  const int ip = blockIdx.x, bh = blockIdx.y;
  const int b = bh >> 4, hh = bh & 15;
  const int tid = threadIdx.x, w = tid >> 6, lane = tid & 63, lo = lane & 15, hi = lane >> 4;
  const int qtA = ip, qtB = 15 - ip;
  const int qw0A = qtA * 128 + w * 32, qw0B = qtB * 128 + w * 32;
  const int ktA = 2 * qtA + 1;       // last K-tile index tile A needs
  const int ktmax = 2 * qtB + 2;     // number of K-tiles tile B needs
  const bool trivial = flags[0] != 0;

  const unsigned short* Qb = Q + (size_t)bh * Sseq * HSn;
  const unsigned short* Kb = Kg + (size_t)bh * Sseq * HSn;
  const unsigned short* Vb = Vt + (size_t)bh * HSn * Sseq;

  // Q fragments (B-operand of swapped QK^T)
  s16x8 qfA[2][2], qfB[2][2];
#pragma unroll
  for (int mq = 0; mq < 2; ++mq)
#pragma unroll
    for (int kk = 0; kk < 2; ++kk) {
      qfA[mq][kk] = *(const s16x8*)&Qb[(size_t)(qw0A + mq * 16 + lo) * HSn + kk * 32 + hi * 8];
      qfB[mq][kk] = *(const s16x8*)&Qb[(size_t)(qw0B + mq * 16 + lo) * HSn + kk * 32 + hi * 8];
    }

  f32x4 oaccA[4][2] = {}, oaccB[4][2] = {};
  float mrunA[2] = {-3e38f, -3e38f}, lrunA[2] = {0.f, 0.f};
  float mrunB[2] = {-3e38f, -3e38f}, lrunB[2] = {0.f, 0.f};

  const int sr = tid >> 2, sc = (tid & 3) * 16;

  // prologue: stage kt=0 into buffer 0
  s16x8 rk0, rk1, rv0, rv1;
  {
    const unsigned short* gk = Kb + (size_t)sr * HSn + sc;
    rk0 = *(const s16x8*)gk; rk1 = *(const s16x8*)(gk + 8);
    const unsigned short* gv = Vb + (size_t)sr * Sseq + sc;
    rv0 = *(const s16x8*)gv; rv1 = *(const s16x8*)(gv + 8);
  }
  *(s16x8*)&kb[0][sr * 72 + sc] = rk0; *(s16x8*)&kb[0][sr * 72 + sc + 8] = rk1;
  *(s16x8*)&vb[0][sr * 72 + sc] = rv0; *(s16x8*)&vb[0][sr * 72 + sc + 8] = rv1;
  __syncthreads();

  for (int kt = 0; kt < ktmax; ++kt) {
    const int cur = kt & 1, k0 = kt * 64;
    const bool pre = (kt + 1 < ktmax);
    if (pre) { // issue next-tile loads early; latency hides under compute
      const int k1 = k0 + 64;
      const unsigned short* gk = Kb + (size_t)(k1 + sr) * HSn + sc;
      rk0 = *(const s16x8*)gk; rk1 = *(const s16x8*)(gk + 8);
      const unsigned short* gv = Vb + (size_t)sr * Sseq + k1 + sc;
      rv0 = *(const s16x8*)gv; rv1 = *(const s16x8*)(gv + 8);
    }
    // load K/V fragments once; shared by both tile calls
    const unsigned short* kbc = kb[cur];
    const unsigned short* vbc = vb[cur];
    s16x8 kfr[4][2], vfr[4][2];
#pragma unroll
    for (int t = 0; t < 4; ++t)
#pragma unroll
      for (int kk = 0; kk < 2; ++kk) {
        kfr[t][kk] = *(const s16x8*)&kbc[(t * 16 + lo) * 72 + kk * 32 + hi * 8];
        vfr[t][kk] = *(const s16x8*)&vbc[(t * 16 + lo) * 72 + kk * 32 + hi * 8];
      }
    if (kt <= ktA)
      attn_tile32(kfr, vfr, qfA, oaccA, mrunA, lrunA, pb[w][0],
                  k0, qw0A, lo, hi, b, pad, tmask, trivial);
    attn_tile32(kfr, vfr, qfB, oaccB, mrunB, lrunB, pb[w][1],
                k0, qw0B, lo, hi, b, pad, tmask, trivial);
    if (pre) { // write-late into the other buffer
      const int nb = cur ^ 1;
      *(s16x8*)&kb[nb][sr * 72 + sc] = rk0; *(s16x8*)&kb[nb][sr * 72 + sc + 8] = rk1;
      *(s16x8*)&vb[nb][sr * 72 + sc] = rv0; *(s16x8*)&vb[nb][sr * 72 + sc + 8] = rv1;
    }
    __syncthreads();
  }

  attn_epilogue32(oaccA, lrunA, pb[w][0], O, b, hh, qw0A, lane, lo, hi);
  attn_epilogue32(oaccB, lrunB, pb[w][1], O, b, hh, qw0B, lane, lo, hi);
}

extern "C" void kernel_launch(void* const* d_in, const int* in_sizes, int n_in,
                              void* d_out, int out_size, void* d_ws, size_t ws_size,
                              hipStream_t stream) {
  const float* x = (const float*)d_in[0];
  const float* y = (const float*)d_in[1];
  const int* pad = (const int*)d_in[2];
  const int* tmask = (const int*)d_in[3];
  const float* Wq = (const float*)d_in[4];
  const float* Wk = (const float*)d_in[5];
  const float* Wv = (const float*)d_in[6];
  const float* Wp = (const float*)d_in[7];
  const float* bp = (const float*)d_in[8];

  char* ws = (char*)d_ws;
  unsigned short* xbf = (unsigned short*)(ws + OFF_XBF);
  unsigned short* ybf = (unsigned short*)(ws + OFF_YBF);
  unsigned short* wqb = (unsigned short*)(ws + OFF_WQ);
  unsigned short* wkb = (unsigned short*)(ws + OFF_WK);
  unsigned short* wvb = (unsigned short*)(ws + OFF_WV);
  unsigned short* wpb = (unsigned short*)(ws + OFF_WP);
  unsigned short* qws = (unsigned short*)(ws + OFF_QWS);
  unsigned short* kws = (unsigned short*)(ws + OFF_KWS);
  unsigned short* vtw = (unsigned short*)(ws + OFF_VTWS);
  unsigned short* ows = (unsigned short*)(ws + OFF_OWS);
  int* flags = (int*)(ws + OFF_FLAG);

  init_flag<<<1, 1, 0, stream>>>(flags);
  check_mask<<<64, 256, 0, stream>>>(pad, Bsz * Sseq, flags);
  check_mask<<<2048, 256, 0, stream>>>(tmask, Sseq * Sseq, flags);

  cvt_all<<<10240, 256, 0, stream>>>(x, y, Wq, Wk, Wv, Wp, ws);

  qkv_gemm<<<dim3(64, 8, 3), 256, 0, stream>>>(xbf, ybf, wqb, wkb, wvb, qws, kws, vtw);

  attn_kernel<<<dim3(8, 64), 256, 0, stream>>>(qws, kws, vtw, ows, pad, tmask, flags);

  gemm_p<<<dim3(64, 8), 256, 0, stream>>>(ows, wpb, (float*)d_out, bp);
}

// Round 7
// 206.585 us; speedup vs baseline: 1.4599x; 1.0459x over previous
//
#include <hip/hip_runtime.h>
#include <hip/hip_bf16.h>
#include <stdint.h>
#include <stddef.h>

// MultiHA: y@Wq^T -> q; x@Wk^T -> k; x@Wv^T -> v; causal softmax attn; @Wp^T + bp
// B=4 S=2048 D=1024 NH=16 HS=64. All GEMM/attn compute in bf16 MFMA, f32 accum.

typedef __attribute__((ext_vector_type(4))) float f32x4;
typedef __attribute__((ext_vector_type(8))) short s16x8;
typedef __attribute__((ext_vector_type(4))) float float4v;
typedef __attribute__((ext_vector_type(2))) unsigned int u32x2;

#define DEV __device__ __forceinline__

constexpr int Bsz = 4, Sseq = 2048, Dm = 1024, NHn = 16, HSn = 64;
// fold 1/sqrt(HS) * log2(e) into Wq so attention softmax runs in exp2 domain
constexpr float QSCALE = 0.125f * 1.4426950408889634f;

// ---- workspace layout (bytes) ----
constexpr size_t SZ_BF_XY = (size_t)Bsz * Sseq * Dm * 2;  // 16 MiB
constexpr size_t SZ_W     = (size_t)Dm * Dm * 2;          // 2 MiB
constexpr size_t OFF_XBF  = 0;
constexpr size_t OFF_YBF  = OFF_XBF + SZ_BF_XY;
constexpr size_t OFF_WQ   = OFF_YBF + SZ_BF_XY;
constexpr size_t OFF_WK   = OFF_WQ + SZ_W;
constexpr size_t OFF_WV   = OFF_WK + SZ_W;
constexpr size_t OFF_WP   = OFF_WV + SZ_W;
constexpr size_t OFF_QWS  = OFF_WP + SZ_W;   // [BH][S][64] bf16
constexpr size_t OFF_KWS  = OFF_QWS + SZ_BF_XY;
constexpr size_t OFF_VTWS = OFF_KWS + SZ_BF_XY; // [BH][64][S] bf16 (V transposed)
constexpr size_t OFF_OWS  = OFF_VTWS + SZ_BF_XY; // attn out [B][S][D] bf16
constexpr size_t OFF_FLAG = OFF_OWS + SZ_BF_XY;

DEV unsigned short f2bf(float f) {
  union { float f; unsigned int u; } v; v.f = f;
  unsigned int r = (v.u + 0x7FFFu + ((v.u >> 16) & 1u)) >> 16;
  return (unsigned short)r;
}

DEV void gll16(const void* g, void* l) {
  __builtin_amdgcn_global_load_lds((const __attribute__((address_space(1))) unsigned int*)g,
                                   (__attribute__((address_space(3))) unsigned int*)l, 16, 0, 0);
}

DEV unsigned int cvtpk(float a, float b) {
  unsigned int r;
  asm("v_cvt_pk_bf16_f32 %0, %1, %2" : "=v"(r) : "v"(a), "v"(b));
  return r;
}

// ---------------- fused fp32 -> bf16 conversion of all inputs ----------------
__global__ void cvt_all(const float* __restrict__ x, const float* __restrict__ y,
                        const float* __restrict__ Wq, const float* __restrict__ Wk,
                        const float* __restrict__ Wv, const float* __restrict__ Wp,
                        char* __restrict__ ws) {
  const int blk = blockIdx.x;
  const float* src;
  unsigned short* dst;
  int b8;
  float scale = 1.f;
  if (blk < 4096)      { src = x;  dst = (unsigned short*)(ws + OFF_XBF); b8 = blk; }
  else if (blk < 8192) { src = y;  dst = (unsigned short*)(ws + OFF_YBF); b8 = blk - 4096; }
  else if (blk < 8704) { src = Wq; dst = (unsigned short*)(ws + OFF_WQ);  b8 = blk - 8192; scale = QSCALE; }
  else if (blk < 9216) { src = Wk; dst = (unsigned short*)(ws + OFF_WK);  b8 = blk - 8704; }
  else if (blk < 9728) { src = Wv; dst = (unsigned short*)(ws + OFF_WV);  b8 = blk - 9216; }
  else                 { src = Wp; dst = (unsigned short*)(ws + OFF_WP);  b8 = blk - 9728; }
  const size_t i = (size_t)b8 * 256 + threadIdx.x;
  const float4v* s = (const float4v*)src + i * 2;
  float4v a = s[0], b = s[1];
  s16x8 o;
  o[0] = (short)f2bf(a[0] * scale); o[1] = (short)f2bf(a[1] * scale);
  o[2] = (short)f2bf(a[2] * scale); o[3] = (short)f2bf(a[3] * scale);
  o[4] = (short)f2bf(b[0] * scale); o[5] = (short)f2bf(b[1] * scale);
  o[6] = (short)f2bf(b[2] * scale); o[7] = (short)f2bf(b[3] * scale);
  *(s16x8*)(dst + i * 8) = o;
}

// ---------------- mask triviality flag ----------------
__global__ void init_flag(int* f) { f[0] = 1; }
__global__ void check_mask(const int* __restrict__ p, int n, int* __restrict__ f) {
  int bad = 0;
  for (int i = blockIdx.x * blockDim.x + threadIdx.x; i < n; i += gridDim.x * blockDim.x)
    bad |= (p[i] == 0);
  if (bad) atomicAnd(f, 0);
}

// ---------------- GEMM main-loop body (128x128 tile, C[m][n] = sum_k A[m][k]*W[n][k]) ----
DEV void gemm_core(const unsigned short* __restrict__ A, const unsigned short* __restrict__ W,
                   unsigned short* __restrict__ lA, unsigned short* __restrict__ lB,
                   f32x4 (&acc)[4][4], int m0, int n0, int w, int lane, int lo, int hi,
                   int wm, int wn) {
  constexpr int K = 1024;
  for (int k0 = 0; k0 < K; k0 += 32) {
#pragma unroll
    for (int h = 0; h < 2; ++h) {
      int c = w * 64 + h * 256 + lane;
      gll16(A + (size_t)(m0 + (c >> 2)) * K + k0 + (c & 3) * 8, lA + (size_t)(w * 64 + h * 256) * 8);
      gll16(W + (size_t)(n0 + (c >> 2)) * K + k0 + (c & 3) * 8, lB + (size_t)(w * 64 + h * 256) * 8);
    }
    __syncthreads();
    s16x8 af[4], bfr[4];
#pragma unroll
    for (int mi = 0; mi < 4; ++mi) af[mi] = *(const s16x8*)&lA[(wm * 64 + mi * 16 + lo) * 32 + hi * 8];
#pragma unroll
    for (int ni = 0; ni < 4; ++ni) bfr[ni] = *(const s16x8*)&lB[(wn * 64 + ni * 16 + lo) * 32 + hi * 8];
#pragma unroll
    for (int mi = 0; mi < 4; ++mi)
#pragma unroll
      for (int ni = 0; ni < 4; ++ni)
        acc[mi][ni] = __builtin_amdgcn_mfma_f32_16x16x32_bf16(af[mi], bfr[ni], acc[mi][ni], 0, 0, 0);
    __syncthreads();
  }
}

// ---------------- fused QKV projection GEMM (grid z: 0=Q, 1=K, 2=V-transposed) ----------
__global__ __launch_bounds__(256) void qkv_gemm(const unsigned short* __restrict__ xbf,
                                                const unsigned short* __restrict__ ybf,
                                                const unsigned short* __restrict__ wqb,
                                                const unsigned short* __restrict__ wkb,
                                                const unsigned short* __restrict__ wvb,
                                                unsigned short* __restrict__ qws,
                                                unsigned short* __restrict__ kws,
                                                unsigned short* __restrict__ vtw) {
  __shared__ unsigned short sm[17408]; // lA(4096) + lB(4096); V-transpose uses 128*136
  unsigned short* lA = sm;
  unsigned short* lB = sm + 4096;
  const int tid = threadIdx.x;
  const int w = tid >> 6, lane = tid & 63, lo = lane & 15, hi = lane >> 4;
  const int wm = w >> 1, wn = w & 1;
  const int m0 = blockIdx.x * 128, n0 = blockIdx.y * 128;
  const int z = blockIdx.z;
  const unsigned short* A = (z == 0) ? ybf : xbf;
  const unsigned short* W = (z == 0) ? wqb : ((z == 1) ? wkb : wvb);
  f32x4 acc[4][4] = {};
  gemm_core(A, W, lA, lB, acc, m0, n0, w, lane, lo, hi, wm, wn);

  if (z <= 1) { // Q / K: bf16 [B,NH,S,HS]
    unsigned short* outb = (z == 0) ? qws : kws;
#pragma unroll
    for (int mi = 0; mi < 4; ++mi)
#pragma unroll
      for (int ni = 0; ni < 4; ++ni)
#pragma unroll
        for (int j = 0; j < 4; ++j) {
          int m = m0 + wm * 64 + mi * 16 + hi * 4 + j;
          int n = n0 + wn * 64 + ni * 16 + lo;
          int b = m >> 11, s = m & 2047, hh = n >> 6, e = n & 63;
          outb[((size_t)(b * NHn + hh) * Sseq + s) * HSn + e] = f2bf(acc[mi][ni][j]);
        }
  } else { // V: bf16 [B,NH,HS,S] via LDS transpose
    __syncthreads();
#pragma unroll
    for (int mi = 0; mi < 4; ++mi)
#pragma unroll
      for (int ni = 0; ni < 4; ++ni)
#pragma unroll
        for (int j = 0; j < 4; ++j) {
          int ml = wm * 64 + mi * 16 + hi * 4 + j;
          int nl = wn * 64 + ni * 16 + lo;
          sm[(size_t)nl * 136 + ml] = f2bf(acc[mi][ni][j]);
        }
    __syncthreads();
    int nl = tid >> 1, half = tid & 1;
    int b = m0 >> 11, hh = (n0 + nl) >> 6, e = (n0 + nl) & 63;
    unsigned short* dst = vtw + ((size_t)(b * NHn + hh) * HSn + e) * Sseq + (m0 & 2047) + half * 64;
#pragma unroll
    for (int i = 0; i < 8; ++i)
      *(s16x8*)(dst + i * 8) = *(const s16x8*)&sm[(size_t)nl * 136 + half * 64 + i * 8];
  }
}

// ---------------- final projection GEMM: fp32 out [M][1024] + bias ----------------
__global__ __launch_bounds__(256) void gemm_p(const unsigned short* __restrict__ A,
                                              const unsigned short* __restrict__ W,
                                              float* __restrict__ outf,
                                              const float* __restrict__ bias) {
  __shared__ unsigned short sm[8192];
  unsigned short* lA = sm;
  unsigned short* lB = sm + 4096;
  const int tid = threadIdx.x;
  const int w = tid >> 6, lane = tid & 63, lo = lane & 15, hi = lane >> 4;
  const int wm = w >> 1, wn = w & 1;
  const int m0 = blockIdx.x * 128, n0 = blockIdx.y * 128;
  f32x4 acc[4][4] = {};
  gemm_core(A, W, lA, lB, acc, m0, n0, w, lane, lo, hi, wm, wn);
  float bv[4];
#pragma unroll
  for (int ni = 0; ni < 4; ++ni) bv[ni] = bias[n0 + wn * 64 + ni * 16 + lo];
#pragma unroll
  for (int mi = 0; mi < 4; ++mi)
#pragma unroll
    for (int ni = 0; ni < 4; ++ni)
#pragma unroll
      for (int j = 0; j < 4; ++j) {
        int m = m0 + wm * 64 + mi * 16 + hi * 4 + j;
        int n = n0 + wn * 64 + ni * 16 + lo;
        outf[(size_t)m * 1024 + n] = acc[mi][ni][j] + bv[ni];
      }
}

// ---------------- flash attention (8-wave blocks, 16 rows/wave, swapped-QK^T) ----------
// Grid (8,64) = 512 blocks = 2/CU, 512 threads = 8 waves -> 16 waves/CU (2x R5).
// Block (ip,bh): q-tiles qtA=ip, qtB=15-ip; wave w owns rows qt*128+w*16..+15 of each.
// Per-block work: 34 uniform 16-row units; K/V staged once per kt (waves 0-3: K,
// waves 4-7: V), double-buffered with issue-early/write-late register staging.
// Unit math = R5-verified swapped layout with mq dimension removed:
// st[t][j] = S[kpos=k0+t*16+hi*4+j][q=qw0+lo]; oacc[et][j] = O^T[e=et*16+hi*4+j][q=qw0+lo].
DEV void attn_unit16(const unsigned short* __restrict__ kbc,
                     const unsigned short* __restrict__ vbc,
                     const s16x8 (&qf)[2], f32x4 (&oacc)[4],
                     float& mrun, float& lrun,
                     unsigned short* __restrict__ pbw,
                     int k0, int qw0, int lo, int hi, int b,
                     const int* __restrict__ pad, const int* __restrict__ tmask,
                     bool trivial) {
  if (k0 > qw0 + 15) return; // wave-uniform: tile entirely above this wave's rows

  // S^T = K Q^T (operand-swapped)
  f32x4 st[4];
#pragma unroll
  for (int t = 0; t < 4; ++t) {
    f32x4 z = {0.f, 0.f, 0.f, 0.f};
#pragma unroll
    for (int kk = 0; kk < 2; ++kk) {
      s16x8 kfr = *(const s16x8*)&kbc[(t * 16 + lo) * 72 + kk * 32 + hi * 8];
      z = __builtin_amdgcn_mfma_f32_16x16x32_bf16(kfr, qf[kk], z, 0, 0, 0);
    }
    st[t] = z;
  }
  const int qg = qw0 + lo;
  if (k0 + 63 > qw0) { // diagonal tiles: causal mask (kpos > q)
#pragma unroll
    for (int t = 0; t < 4; ++t)
#pragma unroll
      for (int j = 0; j < 4; ++j)
        if (k0 + t * 16 + hi * 4 + j > qg) st[t][j] = -3e38f;
  }
  if (!trivial) { // general pad/time masks (not hit for all-ones inputs)
#pragma unroll
    for (int t = 0; t < 4; ++t)
#pragma unroll
      for (int j = 0; j < 4; ++j) {
        int kg = k0 + t * 16 + hi * 4 + j;
        if (!pad[b * Sseq + kg] || !tmask[(size_t)qg * Sseq + kg]) st[t][j] = -3e38f;
      }
  }
  // online softmax for this lane's q-column (lane-local + 2 shuffles over hi-groups)
  float m0v = fmaxf(fmaxf(st[0][0], st[0][1]), fmaxf(st[0][2], st[0][3]));
  float m1v = fmaxf(fmaxf(st[1][0], st[1][1]), fmaxf(st[1][2], st[1][3]));
  float m2v = fmaxf(fmaxf(st[2][0], st[2][1]), fmaxf(st[2][2], st[2][3]));
  float m3v = fmaxf(fmaxf(st[3][0], st[3][1]), fmaxf(st[3][2], st[3][3]));
  float mx = fmaxf(fmaxf(m0v, m1v), fmaxf(m2v, m3v));
  mx = fmaxf(mx, __shfl_xor(mx, 16, 64));
  mx = fmaxf(mx, __shfl_xor(mx, 32, 64));
  const float mnew = fmaxf(mrun, mx);
  const float al = __builtin_amdgcn_exp2f(mrun - mnew);
  mrun = mnew;
  float r0 = 0.f, r1 = 0.f, r2 = 0.f, r3 = 0.f;
#pragma unroll
  for (int j = 0; j < 4; ++j) {
    float p0 = __builtin_amdgcn_exp2f(st[0][j] - mnew); st[0][j] = p0; r0 += p0;
    float p1 = __builtin_amdgcn_exp2f(st[1][j] - mnew); st[1][j] = p1; r1 += p1;
    float p2 = __builtin_amdgcn_exp2f(st[2][j] - mnew); st[2][j] = p2; r2 += p2;
    float p3 = __builtin_amdgcn_exp2f(st[3][j] - mnew); st[3][j] = p3; r3 += p3;
  }
  float rs = (r0 + r1) + (r2 + r3);
  rs += __shfl_xor(rs, 16, 64);
  rs += __shfl_xor(rs, 32, 64);
  lrun = lrun * al + rs;
  // rescale accumulators (lane-local alpha)
#pragma unroll
  for (int et = 0; et < 4; ++et) oacc[et] *= al;
  // pack P column segment -> pb[q][kpos] (b64 writes, 4 kpos each)
#pragma unroll
  for (int t = 0; t < 4; ++t) {
    u32x2 dd = {cvtpk(st[t][0], st[t][1]), cvtpk(st[t][2], st[t][3])};
    *(u32x2*)&pbw[lo * 72 + t * 16 + hi * 4] = dd;
  }
  // O^T += V^T P^T
  s16x8 pf[2];
#pragma unroll
  for (int kk = 0; kk < 2; ++kk)
    pf[kk] = *(const s16x8*)&pbw[lo * 72 + kk * 32 + hi * 8];
#pragma unroll
  for (int et = 0; et < 4; ++et)
#pragma unroll
    for (int kk = 0; kk < 2; ++kk) {
      s16x8 vfr = *(const s16x8*)&vbc[(et * 16 + lo) * 72 + kk * 32 + hi * 8];
      oacc[et] = __builtin_amdgcn_mfma_f32_16x16x32_bf16(vfr, pf[kk], oacc[et], 0, 0, 0);
    }
}

// normalize by l (lane-local) and write O via per-wave LDS transpose (16 rows)
DEV void attn_epi16(f32x4 (&oacc)[4], float lrun,
                    unsigned short* __restrict__ pbw,
                    unsigned short* __restrict__ O, int b, int hh, int qw0,
                    int lane, int lo, int hi) {
  const float inv = 1.f / lrun;
#pragma unroll
  for (int et = 0; et < 4; ++et) {
    f32x4 o = oacc[et] * inv;
    u32x2 d = {cvtpk(o[0], o[1]), cvtpk(o[2], o[3])};
    *(u32x2*)&pbw[lo * 72 + et * 16 + hi * 4] = d;
  }
  int q = lane >> 2, seg = lane & 3;
  unsigned short* dst = O + ((size_t)b * Sseq + qw0 + q) * Dm + hh * HSn + seg * 16;
  *(s16x8*)dst = *(const s16x8*)&pbw[q * 72 + seg * 16];
  *(s16x8*)(dst + 8) = *(const s16x8*)&pbw[q * 72 + seg * 16 + 8];
}

__global__ __launch_bounds__(512, 4) void attn_kernel(const unsigned short* __restrict__ Q,
                                                      const unsigned short* __restrict__ Kg,
                                                      const unsigned short* __restrict__ Vt,
                                                      unsigned short* __restrict__ O,
                                                      const int* __restrict__ pad,
                                                      const int* __restrict__ tmask,
                                                      const int* __restrict__ flags) {
  __shared__ unsigned short kb[2][64 * 72];   // 18.0 KiB
  __shared__ unsigned short vb[2][64 * 72];   // 18.0 KiB
  __shared__ unsigned short pb[8][16 * 72];   // 18.0 KiB (wave-private P scratch)

  const int ip = blockIdx.x, bh = blockIdx.y;
  const int b = bh >> 4, hh = bh & 15;
  const int tid = threadIdx.x, w = tid >> 6, lane = tid & 63, lo = lane & 15, hi = lane >> 4;
  const int qtA = ip, qtB = 15 - ip;
  const int qw0A = qtA * 128 + w * 16, qw0B = qtB * 128 + w * 16;
  const int ktA = 2 * qtA + 1;       // last K-tile index tile A needs (any wave)
  const int ktmax = 2 * qtB + 2;     // number of K-tiles tile B needs
  const bool trivial = flags[0] != 0;

  const unsigned short* Qb = Q + (size_t)bh * Sseq * HSn;
  const unsigned short* Kb = Kg + (size_t)bh * Sseq * HSn;
  const unsigned short* Vb = Vt + (size_t)bh * HSn * Sseq;

  // Q fragments (B-operand of swapped QK^T)
  s16x8 qfA[2], qfB[2];
#pragma unroll
  for (int kk = 0; kk < 2; ++kk) {
    qfA[kk] = *(const s16x8*)&Qb[(size_t)(qw0A + lo) * HSn + kk * 32 + hi * 8];
    qfB[kk] = *(const s16x8*)&Qb[(size_t)(qw0B + lo) * HSn + kk * 32 + hi * 8];
  }

  f32x4 oaccA[4] = {}, oaccB[4] = {};
  float mrunA = -3e38f, lrunA = 0.f, mrunB = -3e38f, lrunB = 0.f;

  // staging: waves 0-3 handle K, waves 4-7 handle V (256 threads each, R5 pattern)
  const int shalf = tid >> 8, st_t = tid & 255;
  const int sr = st_t >> 2, sc = (st_t & 3) * 16;

  // prologue: stage kt=0 into buffer 0
  s16x8 r0, r1;
  if (shalf == 0) {
    const unsigned short* gk = Kb + (size_t)sr * HSn + sc;
    r0 = *(const s16x8*)gk; r1 = *(const s16x8*)(gk + 8);
    *(s16x8*)&kb[0][sr * 72 + sc] = r0; *(s16x8*)&kb[0][sr * 72 + sc + 8] = r1;
  } else {
    const unsigned short* gv = Vb + (size_t)sr * Sseq + sc;
    r0 = *(const s16x8*)gv; r1 = *(const s16x8*)(gv + 8);
    *(s16x8*)&vb[0][sr * 72 + sc] = r0; *(s16x8*)&vb[0][sr * 72 + sc + 8] = r1;
  }
  __syncthreads();

  for (int kt = 0; kt < ktmax; ++kt) {
    const int cur = kt & 1, k0 = kt * 64;
    const bool pre = (kt + 1 < ktmax);
    if (pre) { // issue next-tile loads early; latency hides under compute
      const int k1 = k0 + 64;
      if (shalf == 0) {
        const unsigned short* gk = Kb + (size_t)(k1 + sr) * HSn + sc;
        r0 = *(const s16x8*)gk; r1 = *(const s16x8*)(gk + 8);
      } else {
        const unsigned short* gv = Vb + (size_t)sr * Sseq + k1 + sc;
        r0 = *(const s16x8*)gv; r1 = *(const s16x8*)(gv + 8);
      }
    }
    const unsigned short* kbc = kb[cur];
    const unsigned short* vbc = vb[cur];
    if (kt <= ktA)
      attn_unit16(kbc, vbc, qfA, oaccA, mrunA, lrunA, pb[w],
                  k0, qw0A, lo, hi, b, pad, tmask, trivial);
    attn_unit16(kbc, vbc, qfB, oaccB, mrunB, lrunB, pb[w],
                k0, qw0B, lo, hi, b, pad, tmask, trivial);
    if (pre) { // write-late into the other buffer
      const int nb = cur ^ 1;
      if (shalf == 0) {
        *(s16x8*)&kb[nb][sr * 72 + sc] = r0; *(s16x8*)&kb[nb][sr * 72 + sc + 8] = r1;
      } else {
        *(s16x8*)&vb[nb][sr * 72 + sc] = r0; *(s16x8*)&vb[nb][sr * 72 + sc + 8] = r1;
      }
    }
    __syncthreads();
  }

  attn_epi16(oaccA, lrunA, pb[w], O, b, hh, qw0A, lane, lo, hi);
  attn_epi16(oaccB, lrunB, pb[w], O, b, hh, qw0B, lane, lo, hi);
}

extern "C" void kernel_launch(void* const* d_in, const int* in_sizes, int n_in,
                              void* d_out, int out_size, void* d_ws, size_t ws_size,
                              hipStream_t stream) {
  const float* x = (const float*)d_in[0];
  const float* y = (const float*)d_in[1];
  const int* pad = (const int*)d_in[2];
  const int* tmask = (const int*)d_in[3];
  const float* Wq = (const float*)d_in[4];
  const float* Wk = (const float*)d_in[5];
  const float* Wv = (const float*)d_in[6];
  const float* Wp = (const float*)d_in[7];
  const float* bp = (const float*)d_in[8];

  char* ws = (char*)d_ws;
  unsigned short* xbf = (unsigned short*)(ws + OFF_XBF);
  unsigned short* ybf = (unsigned short*)(ws + OFF_YBF);
  unsigned short* wqb = (unsigned short*)(ws + OFF_WQ);
  unsigned short* wkb = (unsigned short*)(ws + OFF_WK);
  unsigned short* wvb = (unsigned short*)(ws + OFF_WV);
  unsigned short* wpb = (unsigned short*)(ws + OFF_WP);
  unsigned short* qws = (unsigned short*)(ws + OFF_QWS);
  unsigned short* kws = (unsigned short*)(ws + OFF_KWS);
  unsigned short* vtw = (unsigned short*)(ws + OFF_VTWS);
  unsigned short* ows = (unsigned short*)(ws + OFF_OWS);
  int* flags = (int*)(ws + OFF_FLAG);

  init_flag<<<1, 1, 0, stream>>>(flags);
  check_mask<<<64, 256, 0, stream>>>(pad, Bsz * Sseq, flags);
  check_mask<<<2048, 256, 0, stream>>>(tmask, Sseq * Sseq, flags);

  cvt_all<<<10240, 256, 0, stream>>>(x, y, Wq, Wk, Wv, Wp, ws);

  qkv_gemm<<<dim3(64, 8, 3), 256, 0, stream>>>(xbf, ybf, wqb, wkb, wvb, qws, kws, vtw);

  attn_kernel<<<dim3(8, 64), 512, 0, stream>>>(qws, kws, vtw, ows, pad, tmask, flags);

  gemm_p<<<dim3(64, 8), 256, 0, stream>>>(ows, wpb, (float*)d_out, bp);
}

// Round 8
// 199.643 us; speedup vs baseline: 1.5106x; 1.0348x over previous
//
#include <hip/hip_runtime.h>
#include <hip/hip_bf16.h>
#include <stdint.h>
#include <stddef.h>

// MultiHA: y@Wq^T -> q; x@Wk^T -> k; x@Wv^T -> v; causal softmax attn; @Wp^T + bp
// B=4 S=2048 D=1024 NH=16 HS=64. All GEMM/attn compute in bf16 MFMA, f32 accum.

typedef __attribute__((ext_vector_type(4))) float f32x4;
typedef __attribute__((ext_vector_type(8))) short s16x8;
typedef __attribute__((ext_vector_type(4))) float float4v;
typedef __attribute__((ext_vector_type(4))) int i32x4;
typedef __attribute__((ext_vector_type(2))) unsigned int u32x2;

#define DEV __device__ __forceinline__

constexpr int Bsz = 4, Sseq = 2048, Dm = 1024, NHn = 16, HSn = 64;
// fold 1/sqrt(HS) * log2(e) into Wq so attention softmax runs in exp2 domain
constexpr float QSCALE = 0.125f * 1.4426950408889634f;

// ---- workspace layout (bytes) ----
constexpr size_t SZ_BF_XY = (size_t)Bsz * Sseq * Dm * 2;  // 16 MiB
constexpr size_t SZ_W     = (size_t)Dm * Dm * 2;          // 2 MiB
constexpr size_t OFF_XBF  = 0;
constexpr size_t OFF_YBF  = OFF_XBF + SZ_BF_XY;
constexpr size_t OFF_WQ   = OFF_YBF + SZ_BF_XY;
constexpr size_t OFF_WK   = OFF_WQ + SZ_W;
constexpr size_t OFF_WV   = OFF_WK + SZ_W;
constexpr size_t OFF_WP   = OFF_WV + SZ_W;
constexpr size_t OFF_QWS  = OFF_WP + SZ_W;   // [BH][S][64] bf16
constexpr size_t OFF_KWS  = OFF_QWS + SZ_BF_XY;
constexpr size_t OFF_VTWS = OFF_KWS + SZ_BF_XY; // [BH][64][S] bf16 (V transposed)
constexpr size_t OFF_OWS  = OFF_VTWS + SZ_BF_XY; // attn out [B][S][D] bf16
constexpr size_t OFF_FLAG = OFF_OWS + SZ_BF_XY;

DEV unsigned short f2bf(float f) {
  union { float f; unsigned int u; } v; v.f = f;
  unsigned int r = (v.u + 0x7FFFu + ((v.u >> 16) & 1u)) >> 16;
  return (unsigned short)r;
}

DEV void gll16(const void* g, void* l) {
  __builtin_amdgcn_global_load_lds((const __attribute__((address_space(1))) unsigned int*)g,
                                   (__attribute__((address_space(3))) unsigned int*)l, 16, 0, 0);
}

DEV unsigned int cvtpk(float a, float b) {
  unsigned int r;
  asm("v_cvt_pk_bf16_f32 %0, %1, %2" : "=v"(r) : "v"(a), "v"(b));
  return r;
}

// ------ fused fp32->bf16 conversion of all inputs + pad/tmask triviality check ------
// blocks 0..4095: x, 4096..8191: y, 512-chunks: Wq(QSCALE), Wk, Wv, Wp;
// 10240..10247: pad check (int4); 10248..12295: tmask check (2x int4).
// flags[0] preset to 0 by hipMemsetAsync; any zero mask element -> atomicOr 1.
__global__ void cvt_all(const float* __restrict__ x, const float* __restrict__ y,
                        const float* __restrict__ Wq, const float* __restrict__ Wk,
                        const float* __restrict__ Wv, const float* __restrict__ Wp,
                        const int* __restrict__ pad, const int* __restrict__ tmask,
                        char* __restrict__ ws, int* __restrict__ flags) {
  const int blk = blockIdx.x;
  if (blk >= 10240) {
    int bad = 0;
    if (blk < 10248) { // pad: 8192 ints, 4 per thread
      const i32x4 v = ((const i32x4*)pad)[(blk - 10240) * 256 + threadIdx.x];
      bad = (v[0] == 0) | (v[1] == 0) | (v[2] == 0) | (v[3] == 0);
    } else { // tmask: 4M ints, 8 per thread
      const i32x4* tp = (const i32x4*)tmask + ((size_t)(blk - 10248) * 256 + threadIdx.x) * 2;
      i32x4 v0 = tp[0], v1 = tp[1];
      bad = (v0[0] == 0) | (v0[1] == 0) | (v0[2] == 0) | (v0[3] == 0) |
            (v1[0] == 0) | (v1[1] == 0) | (v1[2] == 0) | (v1[3] == 0);
    }
    if (__builtin_amdgcn_ballot_w64(bad) != 0 && (threadIdx.x & 63) == 0)
      atomicOr(flags, 1);
    return;
  }
  const float* src;
  unsigned short* dst;
  int b8;
  float scale = 1.f;
  if (blk < 4096)      { src = x;  dst = (unsigned short*)(ws + OFF_XBF); b8 = blk; }
  else if (blk < 8192) { src = y;  dst = (unsigned short*)(ws + OFF_YBF); b8 = blk - 4096; }
  else if (blk < 8704) { src = Wq; dst = (unsigned short*)(ws + OFF_WQ);  b8 = blk - 8192; scale = QSCALE; }
  else if (blk < 9216) { src = Wk; dst = (unsigned short*)(ws + OFF_WK);  b8 = blk - 8704; }
  else if (blk < 9728) { src = Wv; dst = (unsigned short*)(ws + OFF_WV);  b8 = blk - 9216; }
  else                 { src = Wp; dst = (unsigned short*)(ws + OFF_WP);  b8 = blk - 9728; }
  const size_t i = (size_t)b8 * 256 + threadIdx.x;
  const float4v* s = (const float4v*)src + i * 2;
  float4v a = s[0], b = s[1];
  s16x8 o;
  o[0] = (short)f2bf(a[0] * scale); o[1] = (short)f2bf(a[1] * scale);
  o[2] = (short)f2bf(a[2] * scale); o[3] = (short)f2bf(a[3] * scale);
  o[4] = (short)f2bf(b[0] * scale); o[5] = (short)f2bf(b[1] * scale);
  o[6] = (short)f2bf(b[2] * scale); o[7] = (short)f2bf(b[3] * scale);
  *(s16x8*)(dst + i * 8) = o;
}

// ---------------- Q projection GEMM: C[m][n] = sum_k y[m][k] * Wq[n][k] ----------------
__global__ __launch_bounds__(256) void q_gemm(const unsigned short* __restrict__ A,
                                              const unsigned short* __restrict__ W,
                                              unsigned short* __restrict__ outb) {
  constexpr int K = 1024;
  __shared__ unsigned short sm[8192];
  unsigned short* lA = sm;
  unsigned short* lB = sm + 4096;
  const int tid = threadIdx.x;
  const int w = tid >> 6, lane = tid & 63, lo = lane & 15, hi = lane >> 4;
  const int wm = w >> 1, wn = w & 1;
  const int m0 = blockIdx.x * 128, n0 = blockIdx.y * 128;
  f32x4 acc[4][4] = {};

  for (int k0 = 0; k0 < K; k0 += 32) {
#pragma unroll
    for (int h = 0; h < 2; ++h) {
      int c = w * 64 + h * 256 + lane;
      gll16(A + (size_t)(m0 + (c >> 2)) * K + k0 + (c & 3) * 8, lA + (size_t)(w * 64 + h * 256) * 8);
      gll16(W + (size_t)(n0 + (c >> 2)) * K + k0 + (c & 3) * 8, lB + (size_t)(w * 64 + h * 256) * 8);
    }
    __syncthreads();
    s16x8 af[4], bfr[4];
#pragma unroll
    for (int mi = 0; mi < 4; ++mi) af[mi] = *(const s16x8*)&lA[(wm * 64 + mi * 16 + lo) * 32 + hi * 8];
#pragma unroll
    for (int ni = 0; ni < 4; ++ni) bfr[ni] = *(const s16x8*)&lB[(wn * 64 + ni * 16 + lo) * 32 + hi * 8];
#pragma unroll
    for (int mi = 0; mi < 4; ++mi)
#pragma unroll
      for (int ni = 0; ni < 4; ++ni)
        acc[mi][ni] = __builtin_amdgcn_mfma_f32_16x16x32_bf16(af[mi], bfr[ni], acc[mi][ni], 0, 0, 0);
    __syncthreads();
  }
#pragma unroll
  for (int mi = 0; mi < 4; ++mi)
#pragma unroll
    for (int ni = 0; ni < 4; ++ni)
#pragma unroll
      for (int j = 0; j < 4; ++j) {
        int m = m0 + wm * 64 + mi * 16 + hi * 4 + j;
        int n = n0 + wn * 64 + ni * 16 + lo;
        int b = m >> 11, s = m & 2047, hh = n >> 6, e = n & 63;
        outb[((size_t)(b * NHn + hh) * Sseq + s) * HSn + e] = f2bf(acc[mi][ni][j]);
      }
}

// -------- merged K+V projection GEMM: shared x-tile staging, 32 MFMA per barrier ------
// K out bf16 [B,NH,S,HS]; V out bf16 [B,NH,HS,S] (LDS-transposed epilogue).
__global__ __launch_bounds__(256, 2) void kv_gemm(const unsigned short* __restrict__ A,
                                                  const unsigned short* __restrict__ Wk,
                                                  const unsigned short* __restrict__ Wv,
                                                  unsigned short* __restrict__ kws,
                                                  unsigned short* __restrict__ vtw) {
  constexpr int K = 1024;
  __shared__ unsigned short sm[17408]; // loop: lA+lBk+lBv (12288); epilogue transpose: 128*136
  unsigned short* lA = sm;
  unsigned short* lBk = sm + 4096;
  unsigned short* lBv = sm + 8192;
  const int tid = threadIdx.x;
  const int w = tid >> 6, lane = tid & 63, lo = lane & 15, hi = lane >> 4;
  const int wm = w >> 1, wn = w & 1;
  const int m0 = blockIdx.x * 128, n0 = blockIdx.y * 128;
  f32x4 acck[4][4] = {}, accv[4][4] = {};

  for (int k0 = 0; k0 < K; k0 += 32) {
#pragma unroll
    for (int h = 0; h < 2; ++h) {
      int c = w * 64 + h * 256 + lane;
      size_t roff = (size_t)(c >> 2) * K + k0 + (c & 3) * 8;
      size_t loff = (size_t)(w * 64 + h * 256) * 8;
      gll16(A + (size_t)m0 * K + roff, lA + loff);
      gll16(Wk + (size_t)n0 * K + roff, lBk + loff);
      gll16(Wv + (size_t)n0 * K + roff, lBv + loff);
    }
    __syncthreads();
    s16x8 af[4], bfk[4], bfv[4];
#pragma unroll
    for (int mi = 0; mi < 4; ++mi) af[mi] = *(const s16x8*)&lA[(wm * 64 + mi * 16 + lo) * 32 + hi * 8];
#pragma unroll
    for (int ni = 0; ni < 4; ++ni) {
      bfk[ni] = *(const s16x8*)&lBk[(wn * 64 + ni * 16 + lo) * 32 + hi * 8];
      bfv[ni] = *(const s16x8*)&lBv[(wn * 64 + ni * 16 + lo) * 32 + hi * 8];
    }
#pragma unroll
    for (int mi = 0; mi < 4; ++mi)
#pragma unroll
      for (int ni = 0; ni < 4; ++ni) {
        acck[mi][ni] = __builtin_amdgcn_mfma_f32_16x16x32_bf16(af[mi], bfk[ni], acck[mi][ni], 0, 0, 0);
        accv[mi][ni] = __builtin_amdgcn_mfma_f32_16x16x32_bf16(af[mi], bfv[ni], accv[mi][ni], 0, 0, 0);
      }
    __syncthreads();
  }

  // K epilogue: direct global stores (no LDS)
#pragma unroll
  for (int mi = 0; mi < 4; ++mi)
#pragma unroll
    for (int ni = 0; ni < 4; ++ni)
#pragma unroll
      for (int j = 0; j < 4; ++j) {
        int m = m0 + wm * 64 + mi * 16 + hi * 4 + j;
        int n = n0 + wn * 64 + ni * 16 + lo;
        int b = m >> 11, s = m & 2047, hh = n >> 6, e = n & 63;
        kws[((size_t)(b * NHn + hh) * Sseq + s) * HSn + e] = f2bf(acck[mi][ni][j]);
      }
  // V epilogue: LDS transpose (reuses sm)
  __syncthreads();
#pragma unroll
  for (int mi = 0; mi < 4; ++mi)
#pragma unroll
    for (int ni = 0; ni < 4; ++ni)
#pragma unroll
      for (int j = 0; j < 4; ++j) {
        int ml = wm * 64 + mi * 16 + hi * 4 + j;
        int nl = wn * 64 + ni * 16 + lo;
        sm[(size_t)nl * 136 + ml] = f2bf(accv[mi][ni][j]);
      }
  __syncthreads();
  int nl = tid >> 1, half = tid & 1;
  int b = m0 >> 11, hh = (n0 + nl) >> 6, e = (n0 + nl) & 63;
  unsigned short* dst = vtw + ((size_t)(b * NHn + hh) * HSn + e) * Sseq + (m0 & 2047) + half * 64;
#pragma unroll
  for (int i = 0; i < 8; ++i)
    *(s16x8*)(dst + i * 8) = *(const s16x8*)&sm[(size_t)nl * 136 + half * 64 + i * 8];
}

// ---------------- final projection GEMM: fp32 out [M][1024] + bias ----------------
__global__ __launch_bounds__(256) void gemm_p(const unsigned short* __restrict__ A,
                                              const unsigned short* __restrict__ W,
                                              float* __restrict__ outf,
                                              const float* __restrict__ bias) {
  constexpr int K = 1024;
  __shared__ unsigned short sm[8192];
  unsigned short* lA = sm;
  unsigned short* lB = sm + 4096;
  const int tid = threadIdx.x;
  const int w = tid >> 6, lane = tid & 63, lo = lane & 15, hi = lane >> 4;
  const int wm = w >> 1, wn = w & 1;
  const int m0 = blockIdx.x * 128, n0 = blockIdx.y * 128;
  f32x4 acc[4][4] = {};
  for (int k0 = 0; k0 < K; k0 += 32) {
#pragma unroll
    for (int h = 0; h < 2; ++h) {
      int c = w * 64 + h * 256 + lane;
      gll16(A + (size_t)(m0 + (c >> 2)) * K + k0 + (c & 3) * 8, lA + (size_t)(w * 64 + h * 256) * 8);
      gll16(W + (size_t)(n0 + (c >> 2)) * K + k0 + (c & 3) * 8, lB + (size_t)(w * 64 + h * 256) * 8);
    }
    __syncthreads();
    s16x8 af[4], bfr[4];
#pragma unroll
    for (int mi = 0; mi < 4; ++mi) af[mi] = *(const s16x8*)&lA[(wm * 64 + mi * 16 + lo) * 32 + hi * 8];
#pragma unroll
    for (int ni = 0; ni < 4; ++ni) bfr[ni] = *(const s16x8*)&lB[(wn * 64 + ni * 16 + lo) * 32 + hi * 8];
#pragma unroll
    for (int mi = 0; mi < 4; ++mi)
#pragma unroll
      for (int ni = 0; ni < 4; ++ni)
        acc[mi][ni] = __builtin_amdgcn_mfma_f32_16x16x32_bf16(af[mi], bfr[ni], acc[mi][ni], 0, 0, 0);
    __syncthreads();
  }
  float bv[4];
#pragma unroll
  for (int ni = 0; ni < 4; ++ni) bv[ni] = bias[n0 + wn * 64 + ni * 16 + lo];
#pragma unroll
  for (int mi = 0; mi < 4; ++mi)
#pragma unroll
    for (int ni = 0; ni < 4; ++ni)
#pragma unroll
      for (int j = 0; j < 4; ++j) {
        int m = m0 + wm * 64 + mi * 16 + hi * 4 + j;
        int n = n0 + wn * 64 + ni * 16 + lo;
        outf[(size_t)m * 1024 + n] = acc[mi][ni][j] + bv[ni];
      }
}

// ---------------- flash attention (8-wave blocks, 16 rows/wave, swapped-QK^T) ----------
// Grid (8,64) = 512 blocks = 2/CU, 512 threads = 8 waves -> 16 waves/CU.
// Block (ip,bh): q-tiles qtA=ip, qtB=15-ip; wave w owns rows qt*128+w*16..+15 of each.
// st[t][j] = S[kpos=k0+t*16+hi*4+j][q=qw0+lo]; oacc[et][j] = O^T[e=et*16+hi*4+j][q=qw0+lo].
DEV void attn_unit16(const unsigned short* __restrict__ kbc,
                     const unsigned short* __restrict__ vbc,
                     const s16x8 (&qf)[2], f32x4 (&oacc)[4],
                     float& mrun, float& lrun,
                     unsigned short* __restrict__ pbw,
                     int k0, int qw0, int lo, int hi, int b,
                     const int* __restrict__ pad, const int* __restrict__ tmask,
                     bool trivial) {
  if (k0 > qw0 + 15) return; // wave-uniform: tile entirely above this wave's rows

  // S^T = K Q^T (operand-swapped)
  f32x4 st[4];
#pragma unroll
  for (int t = 0; t < 4; ++t) {
    f32x4 z = {0.f, 0.f, 0.f, 0.f};
#pragma unroll
    for (int kk = 0; kk < 2; ++kk) {
      s16x8 kfr = *(const s16x8*)&kbc[(t * 16 + lo) * 72 + kk * 32 + hi * 8];
      z = __builtin_amdgcn_mfma_f32_16x16x32_bf16(kfr, qf[kk], z, 0, 0, 0);
    }
    st[t] = z;
  }
  const int qg = qw0 + lo;
  if (k0 + 63 > qw0) { // diagonal tiles: causal mask (kpos > q)
#pragma unroll
    for (int t = 0; t < 4; ++t)
#pragma unroll
      for (int j = 0; j < 4; ++j)
        if (k0 + t * 16 + hi * 4 + j > qg) st[t][j] = -3e38f;
  }
  if (!trivial) { // general pad/time masks (not hit for all-ones inputs)
#pragma unroll
    for (int t = 0; t < 4; ++t)
#pragma unroll
      for (int j = 0; j < 4; ++j) {
        int kg = k0 + t * 16 + hi * 4 + j;
        if (!pad[b * Sseq + kg] || !tmask[(size_t)qg * Sseq + kg]) st[t][j] = -3e38f;
      }
  }
  // online softmax for this lane's q-column (lane-local + 2 shuffles over hi-groups)
  float m0v = fmaxf(fmaxf(st[0][0], st[0][1]), fmaxf(st[0][2], st[0][3]));
  float m1v = fmaxf(fmaxf(st[1][0], st[1][1]), fmaxf(st[1][2], st[1][3]));
  float m2v = fmaxf(fmaxf(st[2][0], st[2][1]), fmaxf(st[2][2], st[2][3]));
  float m3v = fmaxf(fmaxf(st[3][0], st[3][1]), fmaxf(st[3][2], st[3][3]));
  float mx = fmaxf(fmaxf(m0v, m1v), fmaxf(m2v, m3v));
  mx = fmaxf(mx, __shfl_xor(mx, 16, 64));
  mx = fmaxf(mx, __shfl_xor(mx, 32, 64));
  const float mnew = fmaxf(mrun, mx);
  const float al = __builtin_amdgcn_exp2f(mrun - mnew);
  mrun = mnew;
  float r0 = 0.f, r1 = 0.f, r2 = 0.f, r3 = 0.f;
#pragma unroll
  for (int j = 0; j < 4; ++j) {
    float p0 = __builtin_amdgcn_exp2f(st[0][j] - mnew); st[0][j] = p0; r0 += p0;
    float p1 = __builtin_amdgcn_exp2f(st[1][j] - mnew); st[1][j] = p1; r1 += p1;
    float p2 = __builtin_amdgcn_exp2f(st[2][j] - mnew); st[2][j] = p2; r2 += p2;
    float p3 = __builtin_amdgcn_exp2f(st[3][j] - mnew); st[3][j] = p3; r3 += p3;
  }
  float rs = (r0 + r1) + (r2 + r3);
  rs += __shfl_xor(rs, 16, 64);
  rs += __shfl_xor(rs, 32, 64);
  lrun = lrun * al + rs;
  // rescale accumulators (lane-local alpha)
#pragma unroll
  for (int et = 0; et < 4; ++et) oacc[et] *= al;
  // pack P column segment -> pb[q][kpos] (b64 writes, 4 kpos each)
#pragma unroll
  for (int t = 0; t < 4; ++t) {
    u32x2 dd = {cvtpk(st[t][0], st[t][1]), cvtpk(st[t][2], st[t][3])};
    *(u32x2*)&pbw[lo * 72 + t * 16 + hi * 4] = dd;
  }
  // O^T += V^T P^T
  s16x8 pf[2];
#pragma unroll
  for (int kk = 0; kk < 2; ++kk)
    pf[kk] = *(const s16x8*)&pbw[lo * 72 + kk * 32 + hi * 8];
#pragma unroll
  for (int et = 0; et < 4; ++et)
#pragma unroll
    for (int kk = 0; kk < 2; ++kk) {
      s16x8 vfr = *(const s16x8*)&vbc[(et * 16 + lo) * 72 + kk * 32 + hi * 8];
      oacc[et] = __builtin_amdgcn_mfma_f32_16x16x32_bf16(vfr, pf[kk], oacc[et], 0, 0, 0);
    }
}

// normalize by l (lane-local) and write O via per-wave LDS transpose (16 rows)
DEV void attn_epi16(f32x4 (&oacc)[4], float lrun,
                    unsigned short* __restrict__ pbw,
                    unsigned short* __restrict__ O, int b, int hh, int qw0,
                    int lane, int lo, int hi) {
  const float inv = 1.f / lrun;
#pragma unroll
  for (int et = 0; et < 4; ++et) {
    f32x4 o = oacc[et] * inv;
    u32x2 d = {cvtpk(o[0], o[1]), cvtpk(o[2], o[3])};
    *(u32x2*)&pbw[lo * 72 + et * 16 + hi * 4] = d;
  }
  int q = lane >> 2, seg = lane & 3;
  unsigned short* dst = O + ((size_t)b * Sseq + qw0 + q) * Dm + hh * HSn + seg * 16;
  *(s16x8*)dst = *(const s16x8*)&pbw[q * 72 + seg * 16];
  *(s16x8*)(dst + 8) = *(const s16x8*)&pbw[q * 72 + seg * 16 + 8];
}

__global__ __launch_bounds__(512, 4) void attn_kernel(const unsigned short* __restrict__ Q,
                                                      const unsigned short* __restrict__ Kg,
                                                      const unsigned short* __restrict__ Vt,
                                                      unsigned short* __restrict__ O,
                                                      const int* __restrict__ pad,
                                                      const int* __restrict__ tmask,
                                                      const int* __restrict__ flags) {
  __shared__ unsigned short kb[2][64 * 72];   // 18.0 KiB
  __shared__ unsigned short vb[2][64 * 72];   // 18.0 KiB
  __shared__ unsigned short pb[8][16 * 72];   // 18.0 KiB (wave-private P scratch)

  const int ip = blockIdx.x, bh = blockIdx.y;
  const int b = bh >> 4, hh = bh & 15;
  const int tid = threadIdx.x, w = tid >> 6, lane = tid & 63, lo = lane & 15, hi = lane >> 4;
  const int qtA = ip, qtB = 15 - ip;
  const int qw0A = qtA * 128 + w * 16, qw0B = qtB * 128 + w * 16;
  const int ktA = 2 * qtA + 1;       // last K-tile index tile A needs (any wave)
  const int ktmax = 2 * qtB + 2;     // number of K-tiles tile B needs
  const bool trivial = flags[0] == 0;

  const unsigned short* Qb = Q + (size_t)bh * Sseq * HSn;
  const unsigned short* Kb = Kg + (size_t)bh * Sseq * HSn;
  const unsigned short* Vb = Vt + (size_t)bh * HSn * Sseq;

  // Q fragments (B-operand of swapped QK^T)
  s16x8 qfA[2], qfB[2];
#pragma unroll
  for (int kk = 0; kk < 2; ++kk) {
    qfA[kk] = *(const s16x8*)&Qb[(size_t)(qw0A + lo) * HSn + kk * 32 + hi * 8];
    qfB[kk] = *(const s16x8*)&Qb[(size_t)(qw0B + lo) * HSn + kk * 32 + hi * 8];
  }

  f32x4 oaccA[4] = {}, oaccB[4] = {};
  float mrunA = -3e38f, lrunA = 0.f, mrunB = -3e38f, lrunB = 0.f;

  // staging: waves 0-3 handle K, waves 4-7 handle V (256 threads each)
  const int shalf = tid >> 8, st_t = tid & 255;
  const int sr = st_t >> 2, sc = (st_t & 3) * 16;

  // prologue: stage kt=0 into buffer 0
  s16x8 r0, r1;
  if (shalf == 0) {
    const unsigned short* gk = Kb + (size_t)sr * HSn + sc;
    r0 = *(const s16x8*)gk; r1 = *(const s16x8*)(gk + 8);
    *(s16x8*)&kb[0][sr * 72 + sc] = r0; *(s16x8*)&kb[0][sr * 72 + sc + 8] = r1;
  } else {
    const unsigned short* gv = Vb + (size_t)sr * Sseq + sc;
    r0 = *(const s16x8*)gv; r1 = *(const s16x8*)(gv + 8);
    *(s16x8*)&vb[0][sr * 72 + sc] = r0; *(s16x8*)&vb[0][sr * 72 + sc + 8] = r1;
  }
  __syncthreads();

  for (int kt = 0; kt < ktmax; ++kt) {
    const int cur = kt & 1, k0 = kt * 64;
    const bool pre = (kt + 1 < ktmax);
    if (pre) { // issue next-tile loads early; latency hides under compute
      const int k1 = k0 + 64;
      if (shalf == 0) {
        const unsigned short* gk = Kb + (size_t)(k1 + sr) * HSn + sc;
        r0 = *(const s16x8*)gk; r1 = *(const s16x8*)(gk + 8);
      } else {
        const unsigned short* gv = Vb + (size_t)sr * Sseq + k1 + sc;
        r0 = *(const s16x8*)gv; r1 = *(const s16x8*)(gv + 8);
      }
    }
    const unsigned short* kbc = kb[cur];
    const unsigned short* vbc = vb[cur];
    if (kt <= ktA)
      attn_unit16(kbc, vbc, qfA, oaccA, mrunA, lrunA, pb[w],
                  k0, qw0A, lo, hi, b, pad, tmask, trivial);
    attn_unit16(kbc, vbc, qfB, oaccB, mrunB, lrunB, pb[w],
                k0, qw0B, lo, hi, b, pad, tmask, trivial);
    if (pre) { // write-late into the other buffer
      const int nb = cur ^ 1;
      if (shalf == 0) {
        *(s16x8*)&kb[nb][sr * 72 + sc] = r0; *(s16x8*)&kb[nb][sr * 72 + sc + 8] = r1;
      } else {
        *(s16x8*)&vb[nb][sr * 72 + sc] = r0; *(s16x8*)&vb[nb][sr * 72 + sc + 8] = r1;
      }
    }
    __syncthreads();
  }

  attn_epi16(oaccA, lrunA, pb[w], O, b, hh, qw0A, lane, lo, hi);
  attn_epi16(oaccB, lrunB, pb[w], O, b, hh, qw0B, lane, lo, hi);
}

extern "C" void kernel_launch(void* const* d_in, const int* in_sizes, int n_in,
                              void* d_out, int out_size, void* d_ws, size_t ws_size,
                              hipStream_t stream) {
  const float* x = (const float*)d_in[0];
  const float* y = (const float*)d_in[1];
  const int* pad = (const int*)d_in[2];
  const int* tmask = (const int*)d_in[3];
  const float* Wq = (const float*)d_in[4];
  const float* Wk = (const float*)d_in[5];
  const float* Wv = (const float*)d_in[6];
  const float* Wp = (const float*)d_in[7];
  const float* bp = (const float*)d_in[8];

  char* ws = (char*)d_ws;
  unsigned short* xbf = (unsigned short*)(ws + OFF_XBF);
  unsigned short* ybf = (unsigned short*)(ws + OFF_YBF);
  unsigned short* wqb = (unsigned short*)(ws + OFF_WQ);
  unsigned short* wkb = (unsigned short*)(ws + OFF_WK);
  unsigned short* wvb = (unsigned short*)(ws + OFF_WV);
  unsigned short* wpb = (unsigned short*)(ws + OFF_WP);
  unsigned short* qws = (unsigned short*)(ws + OFF_QWS);
  unsigned short* kws = (unsigned short*)(ws + OFF_KWS);
  unsigned short* vtw = (unsigned short*)(ws + OFF_VTWS);
  unsigned short* ows = (unsigned short*)(ws + OFF_OWS);
  int* flags = (int*)(ws + OFF_FLAG);

  hipMemsetAsync(flags, 0, 4, stream);
  cvt_all<<<12296, 256, 0, stream>>>(x, y, Wq, Wk, Wv, Wp, pad, tmask, ws, flags);

  q_gemm<<<dim3(64, 8), 256, 0, stream>>>(ybf, wqb, qws);
  kv_gemm<<<dim3(64, 8), 256, 0, stream>>>(xbf, wkb, wvb, kws, vtw);

  attn_kernel<<<dim3(8, 64), 512, 0, stream>>>(qws, kws, vtw, ows, pad, tmask, flags);

  gemm_p<<<dim3(64, 8), 256, 0, stream>>>(ows, wpb, (float*)d_out, bp);
}

// Round 9
// 192.773 us; speedup vs baseline: 1.5645x; 1.0356x over previous
//
#include <hip/hip_runtime.h>
#include <hip/hip_bf16.h>
#include <stdint.h>
#include <stddef.h>

// MultiHA: y@Wq^T -> q; x@Wk^T -> k; x@Wv^T -> v; causal softmax attn; @Wp^T + bp
// B=4 S=2048 D=1024 NH=16 HS=64. All GEMM/attn compute in bf16 MFMA, f32 accum.

typedef __attribute__((ext_vector_type(4))) float f32x4;
typedef __attribute__((ext_vector_type(8))) short s16x8;
typedef __attribute__((ext_vector_type(4))) float float4v;
typedef __attribute__((ext_vector_type(4))) int i32x4;
typedef __attribute__((ext_vector_type(2))) unsigned int u32x2;

#define DEV __device__ __forceinline__

constexpr int Bsz = 4, Sseq = 2048, Dm = 1024, NHn = 16, HSn = 64;
// fold 1/sqrt(HS) * log2(e) into Wq so attention softmax runs in exp2 domain
constexpr float QSCALE = 0.125f * 1.4426950408889634f;

// ---- workspace layout (bytes) ----
constexpr size_t SZ_BF_XY = (size_t)Bsz * Sseq * Dm * 2;  // 16 MiB
constexpr size_t SZ_W     = (size_t)Dm * Dm * 2;          // 2 MiB
constexpr size_t OFF_XBF  = 0;
constexpr size_t OFF_YBF  = OFF_XBF + SZ_BF_XY;
constexpr size_t OFF_WQ   = OFF_YBF + SZ_BF_XY;
constexpr size_t OFF_WK   = OFF_WQ + SZ_W;
constexpr size_t OFF_WV   = OFF_WK + SZ_W;
constexpr size_t OFF_WP   = OFF_WV + SZ_W;
constexpr size_t OFF_QWS  = OFF_WP + SZ_W;   // [BH][S][64] bf16
constexpr size_t OFF_KWS  = OFF_QWS + SZ_BF_XY;
constexpr size_t OFF_VTWS = OFF_KWS + SZ_BF_XY; // [BH][64][S] bf16 (V transposed)
constexpr size_t OFF_OWS  = OFF_VTWS + SZ_BF_XY; // attn out [B][S][D] bf16
constexpr size_t OFF_FLAG = OFF_OWS + SZ_BF_XY;

DEV unsigned short f2bf(float f) {
  union { float f; unsigned int u; } v; v.f = f;
  unsigned int r = (v.u + 0x7FFFu + ((v.u >> 16) & 1u)) >> 16;
  return (unsigned short)r;
}

DEV void gll16(const void* g, void* l) {
  __builtin_amdgcn_global_load_lds((const __attribute__((address_space(1))) unsigned int*)g,
                                   (__attribute__((address_space(3))) unsigned int*)l, 16, 0, 0);
}

DEV unsigned int cvtpk(float a, float b) {
  unsigned int r;
  asm("v_cvt_pk_bf16_f32 %0, %1, %2" : "=v"(r) : "v"(a), "v"(b));
  return r;
}

// ------ fused fp32->bf16 conversion of all inputs + pad/tmask triviality check ------
// blocks 0..4095: x, 4096..8191: y, 512-chunks: Wq(QSCALE), Wk, Wv, Wp;
// 10240..10247: pad check (int4); 10248..12295: tmask check (2x int4).
// flags[0] preset to 0 by hipMemsetAsync; any zero mask element -> atomicOr 1.
__global__ void cvt_all(const float* __restrict__ x, const float* __restrict__ y,
                        const float* __restrict__ Wq, const float* __restrict__ Wk,
                        const float* __restrict__ Wv, const float* __restrict__ Wp,
                        const int* __restrict__ pad, const int* __restrict__ tmask,
                        char* __restrict__ ws, int* __restrict__ flags) {
  const int blk = blockIdx.x;
  if (blk >= 10240) {
    int bad = 0;
    if (blk < 10248) { // pad: 8192 ints, 4 per thread
      const i32x4 v = ((const i32x4*)pad)[(blk - 10240) * 256 + threadIdx.x];
      bad = (v[0] == 0) | (v[1] == 0) | (v[2] == 0) | (v[3] == 0);
    } else { // tmask: 4M ints, 8 per thread
      const i32x4* tp = (const i32x4*)tmask + ((size_t)(blk - 10248) * 256 + threadIdx.x) * 2;
      i32x4 v0 = tp[0], v1 = tp[1];
      bad = (v0[0] == 0) | (v0[1] == 0) | (v0[2] == 0) | (v0[3] == 0) |
            (v1[0] == 0) | (v1[1] == 0) | (v1[2] == 0) | (v1[3] == 0);
    }
    if (__builtin_amdgcn_ballot_w64(bad) != 0 && (threadIdx.x & 63) == 0)
      atomicOr(flags, 1);
    return;
  }
  const float* src;
  unsigned short* dst;
  int b8;
  float scale = 1.f;
  if (blk < 4096)      { src = x;  dst = (unsigned short*)(ws + OFF_XBF); b8 = blk; }
  else if (blk < 8192) { src = y;  dst = (unsigned short*)(ws + OFF_YBF); b8 = blk - 4096; }
  else if (blk < 8704) { src = Wq; dst = (unsigned short*)(ws + OFF_WQ);  b8 = blk - 8192; scale = QSCALE; }
  else if (blk < 9216) { src = Wk; dst = (unsigned short*)(ws + OFF_WK);  b8 = blk - 8704; }
  else if (blk < 9728) { src = Wv; dst = (unsigned short*)(ws + OFF_WV);  b8 = blk - 9216; }
  else                 { src = Wp; dst = (unsigned short*)(ws + OFF_WP);  b8 = blk - 9728; }
  const size_t i = (size_t)b8 * 256 + threadIdx.x;
  const float4v* s = (const float4v*)src + i * 2;
  float4v a = s[0], b = s[1];
  s16x8 o;
  o[0] = (short)f2bf(a[0] * scale); o[1] = (short)f2bf(a[1] * scale);
  o[2] = (short)f2bf(a[2] * scale); o[3] = (short)f2bf(a[3] * scale);
  o[4] = (short)f2bf(b[0] * scale); o[5] = (short)f2bf(b[1] * scale);
  o[6] = (short)f2bf(b[2] * scale); o[7] = (short)f2bf(b[3] * scale);
  *(s16x8*)(dst + i * 8) = o;
}

// ---------------- Q projection GEMM: C[m][n] = sum_k y[m][k] * Wq[n][k] ----------------
__global__ __launch_bounds__(256) void q_gemm(const unsigned short* __restrict__ A,
                                              const unsigned short* __restrict__ W,
                                              unsigned short* __restrict__ outb) {
  constexpr int K = 1024;
  __shared__ unsigned short sm[8192];
  unsigned short* lA = sm;
  unsigned short* lB = sm + 4096;
  const int tid = threadIdx.x;
  const int w = tid >> 6, lane = tid & 63, lo = lane & 15, hi = lane >> 4;
  const int wm = w >> 1, wn = w & 1;
  const int m0 = blockIdx.x * 128, n0 = blockIdx.y * 128;
  f32x4 acc[4][4] = {};

  for (int k0 = 0; k0 < K; k0 += 32) {
#pragma unroll
    for (int h = 0; h < 2; ++h) {
      int c = w * 64 + h * 256 + lane;
      gll16(A + (size_t)(m0 + (c >> 2)) * K + k0 + (c & 3) * 8, lA + (size_t)(w * 64 + h * 256) * 8);
      gll16(W + (size_t)(n0 + (c >> 2)) * K + k0 + (c & 3) * 8, lB + (size_t)(w * 64 + h * 256) * 8);
    }
    __syncthreads();
    s16x8 af[4], bfr[4];
#pragma unroll
    for (int mi = 0; mi < 4; ++mi) af[mi] = *(const s16x8*)&lA[(wm * 64 + mi * 16 + lo) * 32 + hi * 8];
#pragma unroll
    for (int ni = 0; ni < 4; ++ni) bfr[ni] = *(const s16x8*)&lB[(wn * 64 + ni * 16 + lo) * 32 + hi * 8];
#pragma unroll
    for (int mi = 0; mi < 4; ++mi)
#pragma unroll
      for (int ni = 0; ni < 4; ++ni)
        acc[mi][ni] = __builtin_amdgcn_mfma_f32_16x16x32_bf16(af[mi], bfr[ni], acc[mi][ni], 0, 0, 0);
    __syncthreads();
  }
#pragma unroll
  for (int mi = 0; mi < 4; ++mi)
#pragma unroll
    for (int ni = 0; ni < 4; ++ni)
#pragma unroll
      for (int j = 0; j < 4; ++j) {
        int m = m0 + wm * 64 + mi * 16 + hi * 4 + j;
        int n = n0 + wn * 64 + ni * 16 + lo;
        int b = m >> 11, s = m & 2047, hh = n >> 6, e = n & 63;
        outb[((size_t)(b * NHn + hh) * Sseq + s) * HSn + e] = f2bf(acc[mi][ni][j]);
      }
}

// -------- merged K+V projection GEMM: shared x-tile staging, 32 MFMA per barrier ------
// K out bf16 [B,NH,S,HS]; V out bf16 [B,NH,HS,S] (LDS-transposed epilogue).
__global__ __launch_bounds__(256, 2) void kv_gemm(const unsigned short* __restrict__ A,
                                                  const unsigned short* __restrict__ Wk,
                                                  const unsigned short* __restrict__ Wv,
                                                  unsigned short* __restrict__ kws,
                                                  unsigned short* __restrict__ vtw) {
  constexpr int K = 1024;
  __shared__ unsigned short sm[17408]; // loop: lA+lBk+lBv (12288); epilogue transpose: 128*136
  unsigned short* lA = sm;
  unsigned short* lBk = sm + 4096;
  unsigned short* lBv = sm + 8192;
  const int tid = threadIdx.x;
  const int w = tid >> 6, lane = tid & 63, lo = lane & 15, hi = lane >> 4;
  const int wm = w >> 1, wn = w & 1;
  const int m0 = blockIdx.x * 128, n0 = blockIdx.y * 128;
  f32x4 acck[4][4] = {}, accv[4][4] = {};

  for (int k0 = 0; k0 < K; k0 += 32) {
#pragma unroll
    for (int h = 0; h < 2; ++h) {
      int c = w * 64 + h * 256 + lane;
      size_t roff = (size_t)(c >> 2) * K + k0 + (c & 3) * 8;
      size_t loff = (size_t)(w * 64 + h * 256) * 8;
      gll16(A + (size_t)m0 * K + roff, lA + loff);
      gll16(Wk + (size_t)n0 * K + roff, lBk + loff);
      gll16(Wv + (size_t)n0 * K + roff, lBv + loff);
    }
    __syncthreads();
    s16x8 af[4], bfk[4], bfv[4];
#pragma unroll
    for (int mi = 0; mi < 4; ++mi) af[mi] = *(const s16x8*)&lA[(wm * 64 + mi * 16 + lo) * 32 + hi * 8];
#pragma unroll
    for (int ni = 0; ni < 4; ++ni) {
      bfk[ni] = *(const s16x8*)&lBk[(wn * 64 + ni * 16 + lo) * 32 + hi * 8];
      bfv[ni] = *(const s16x8*)&lBv[(wn * 64 + ni * 16 + lo) * 32 + hi * 8];
    }
#pragma unroll
    for (int mi = 0; mi < 4; ++mi)
#pragma unroll
      for (int ni = 0; ni < 4; ++ni) {
        acck[mi][ni] = __builtin_amdgcn_mfma_f32_16x16x32_bf16(af[mi], bfk[ni], acck[mi][ni], 0, 0, 0);
        accv[mi][ni] = __builtin_amdgcn_mfma_f32_16x16x32_bf16(af[mi], bfv[ni], accv[mi][ni], 0, 0, 0);
      }
    __syncthreads();
  }

  // K epilogue: direct global stores (no LDS)
#pragma unroll
  for (int mi = 0; mi < 4; ++mi)
#pragma unroll
    for (int ni = 0; ni < 4; ++ni)
#pragma unroll
      for (int j = 0; j < 4; ++j) {
        int m = m0 + wm * 64 + mi * 16 + hi * 4 + j;
        int n = n0 + wn * 64 + ni * 16 + lo;
        int b = m >> 11, s = m & 2047, hh = n >> 6, e = n & 63;
        kws[((size_t)(b * NHn + hh) * Sseq + s) * HSn + e] = f2bf(acck[mi][ni][j]);
      }
  // V epilogue: LDS transpose (reuses sm)
  __syncthreads();
#pragma unroll
  for (int mi = 0; mi < 4; ++mi)
#pragma unroll
    for (int ni = 0; ni < 4; ++ni)
#pragma unroll
      for (int j = 0; j < 4; ++j) {
        int ml = wm * 64 + mi * 16 + hi * 4 + j;
        int nl = wn * 64 + ni * 16 + lo;
        sm[(size_t)nl * 136 + ml] = f2bf(accv[mi][ni][j]);
      }
  __syncthreads();
  int nl = tid >> 1, half = tid & 1;
  int b = m0 >> 11, hh = (n0 + nl) >> 6, e = (n0 + nl) & 63;
  unsigned short* dst = vtw + ((size_t)(b * NHn + hh) * HSn + e) * Sseq + (m0 & 2047) + half * 64;
#pragma unroll
  for (int i = 0; i < 8; ++i)
    *(s16x8*)(dst + i * 8) = *(const s16x8*)&sm[(size_t)nl * 136 + half * 64 + i * 8];
}

// ---------------- final projection GEMM: fp32 out [M][1024] + bias ----------------
__global__ __launch_bounds__(256) void gemm_p(const unsigned short* __restrict__ A,
                                              const unsigned short* __restrict__ W,
                                              float* __restrict__ outf,
                                              const float* __restrict__ bias) {
  constexpr int K = 1024;
  __shared__ unsigned short sm[8192];
  unsigned short* lA = sm;
  unsigned short* lB = sm + 4096;
  const int tid = threadIdx.x;
  const int w = tid >> 6, lane = tid & 63, lo = lane & 15, hi = lane >> 4;
  const int wm = w >> 1, wn = w & 1;
  const int m0 = blockIdx.x * 128, n0 = blockIdx.y * 128;
  f32x4 acc[4][4] = {};
  for (int k0 = 0; k0 < K; k0 += 32) {
#pragma unroll
    for (int h = 0; h < 2; ++h) {
      int c = w * 64 + h * 256 + lane;
      gll16(A + (size_t)(m0 + (c >> 2)) * K + k0 + (c & 3) * 8, lA + (size_t)(w * 64 + h * 256) * 8);
      gll16(W + (size_t)(n0 + (c >> 2)) * K + k0 + (c & 3) * 8, lB + (size_t)(w * 64 + h * 256) * 8);
    }
    __syncthreads();
    s16x8 af[4], bfr[4];
#pragma unroll
    for (int mi = 0; mi < 4; ++mi) af[mi] = *(const s16x8*)&lA[(wm * 64 + mi * 16 + lo) * 32 + hi * 8];
#pragma unroll
    for (int ni = 0; ni < 4; ++ni) bfr[ni] = *(const s16x8*)&lB[(wn * 64 + ni * 16 + lo) * 32 + hi * 8];
#pragma unroll
    for (int mi = 0; mi < 4; ++mi)
#pragma unroll
      for (int ni = 0; ni < 4; ++ni)
        acc[mi][ni] = __builtin_amdgcn_mfma_f32_16x16x32_bf16(af[mi], bfr[ni], acc[mi][ni], 0, 0, 0);
    __syncthreads();
  }
  float bv[4];
#pragma unroll
  for (int ni = 0; ni < 4; ++ni) bv[ni] = bias[n0 + wn * 64 + ni * 16 + lo];
#pragma unroll
  for (int mi = 0; mi < 4; ++mi)
#pragma unroll
    for (int ni = 0; ni < 4; ++ni)
#pragma unroll
      for (int j = 0; j < 4; ++j) {
        int m = m0 + wm * 64 + mi * 16 + hi * 4 + j;
        int n = n0 + wn * 64 + ni * 16 + lo;
        outf[(size_t)m * 1024 + n] = acc[mi][ni][j] + bv[ni];
      }
}

// ---------------- flash attention (8-wave blocks, 16 rows/wave, swapped-QK^T) ----------
// Grid (8,64) = 512 blocks = 2/CU, 512 threads = 8 waves -> 16 waves/CU.
// Block (ip,bh): q-tiles qtA=ip, qtB=15-ip; wave w owns rows qt*128+w*16..+15 of each.
// st[t][j] = S[kpos=k0+t*16+hi*4+j][q=qw0+lo]; oacc[et][j] = O^T[e=et*16+hi*4+j][q=qw0+lo].
// R9: (1) defer-max (skip rescale unless tile max exceeds running max + 11 in exp2
// domain -> P bounded by 2^11, f32/bf16 safe); (2) l computed by an extra MFMA with
// an all-ones A-operand (every output row = sum_kpos P[kpos][q]) -> removes the
// 16-add + 2-shuffle row-sum per unit.
DEV void attn_unit16(const unsigned short* __restrict__ kbc,
                     const unsigned short* __restrict__ vbc,
                     const s16x8 (&qf)[2], f32x4 (&oacc)[4], f32x4& lacc,
                     float& mrun, const s16x8& ones,
                     unsigned short* __restrict__ pbw,
                     int k0, int qw0, int lo, int hi, int b,
                     const int* __restrict__ pad, const int* __restrict__ tmask,
                     bool trivial) {
  if (k0 > qw0 + 15) return; // wave-uniform: tile entirely above this wave's rows

  // S^T = K Q^T (operand-swapped)
  f32x4 st[4];
#pragma unroll
  for (int t = 0; t < 4; ++t) {
    f32x4 z = {0.f, 0.f, 0.f, 0.f};
#pragma unroll
    for (int kk = 0; kk < 2; ++kk) {
      s16x8 kfr = *(const s16x8*)&kbc[(t * 16 + lo) * 72 + kk * 32 + hi * 8];
      z = __builtin_amdgcn_mfma_f32_16x16x32_bf16(kfr, qf[kk], z, 0, 0, 0);
    }
    st[t] = z;
  }
  const int qg = qw0 + lo;
  if (k0 + 63 > qw0) { // diagonal tiles: causal mask (kpos > q)
#pragma unroll
    for (int t = 0; t < 4; ++t)
#pragma unroll
      for (int j = 0; j < 4; ++j)
        if (k0 + t * 16 + hi * 4 + j > qg) st[t][j] = -3e38f;
  }
  if (!trivial) { // general pad/time masks (not hit for all-ones inputs)
#pragma unroll
    for (int t = 0; t < 4; ++t)
#pragma unroll
      for (int j = 0; j < 4; ++j) {
        int kg = k0 + t * 16 + hi * 4 + j;
        if (!pad[b * Sseq + kg] || !tmask[(size_t)qg * Sseq + kg]) st[t][j] = -3e38f;
      }
  }
  // tile max for this lane's q-column (lane-local + 2 shuffles over hi-groups)
  float m0v = fmaxf(fmaxf(st[0][0], st[0][1]), fmaxf(st[0][2], st[0][3]));
  float m1v = fmaxf(fmaxf(st[1][0], st[1][1]), fmaxf(st[1][2], st[1][3]));
  float m2v = fmaxf(fmaxf(st[2][0], st[2][1]), fmaxf(st[2][2], st[2][3]));
  float m3v = fmaxf(fmaxf(st[3][0], st[3][1]), fmaxf(st[3][2], st[3][3]));
  float mx = fmaxf(fmaxf(m0v, m1v), fmaxf(m2v, m3v));
  mx = fmaxf(mx, __shfl_xor(mx, 16, 64));
  mx = fmaxf(mx, __shfl_xor(mx, 32, 64));
  // defer-max: only rescale when the bound would be exceeded (P <= 2^11 otherwise)
  if (!__all(mx <= mrun + 11.f)) {
    const float mnew = fmaxf(mrun, mx);
    const float al = __builtin_amdgcn_exp2f(mrun - mnew);
    mrun = mnew;
#pragma unroll
    for (int et = 0; et < 4; ++et) oacc[et] *= al;
    lacc *= al;
  }
  // P = exp2(S - mrun)
#pragma unroll
  for (int t = 0; t < 4; ++t)
#pragma unroll
    for (int j = 0; j < 4; ++j)
      st[t][j] = __builtin_amdgcn_exp2f(st[t][j] - mrun);
  // pack P column segment -> pb[q][kpos] (b64 writes, 4 kpos each)
#pragma unroll
  for (int t = 0; t < 4; ++t) {
    u32x2 dd = {cvtpk(st[t][0], st[t][1]), cvtpk(st[t][2], st[t][3])};
    *(u32x2*)&pbw[lo * 72 + t * 16 + hi * 4] = dd;
  }
  // O^T += V^T P^T ; l += ones . P (extra MFMA pair, all rows equal l[q])
  s16x8 pf[2];
#pragma unroll
  for (int kk = 0; kk < 2; ++kk)
    pf[kk] = *(const s16x8*)&pbw[lo * 72 + kk * 32 + hi * 8];
#pragma unroll
  for (int et = 0; et < 4; ++et)
#pragma unroll
    for (int kk = 0; kk < 2; ++kk) {
      s16x8 vfr = *(const s16x8*)&vbc[(et * 16 + lo) * 72 + kk * 32 + hi * 8];
      oacc[et] = __builtin_amdgcn_mfma_f32_16x16x32_bf16(vfr, pf[kk], oacc[et], 0, 0, 0);
    }
  lacc = __builtin_amdgcn_mfma_f32_16x16x32_bf16(ones, pf[0], lacc, 0, 0, 0);
  lacc = __builtin_amdgcn_mfma_f32_16x16x32_bf16(ones, pf[1], lacc, 0, 0, 0);
}

// normalize by l (lane-local) and write O via per-wave LDS transpose (16 rows)
DEV void attn_epi16(f32x4 (&oacc)[4], float lrun,
                    unsigned short* __restrict__ pbw,
                    unsigned short* __restrict__ O, int b, int hh, int qw0,
                    int lane, int lo, int hi) {
  const float inv = 1.f / lrun;
#pragma unroll
  for (int et = 0; et < 4; ++et) {
    f32x4 o = oacc[et] * inv;
    u32x2 d = {cvtpk(o[0], o[1]), cvtpk(o[2], o[3])};
    *(u32x2*)&pbw[lo * 72 + et * 16 + hi * 4] = d;
  }
  int q = lane >> 2, seg = lane & 3;
  unsigned short* dst = O + ((size_t)b * Sseq + qw0 + q) * Dm + hh * HSn + seg * 16;
  *(s16x8*)dst = *(const s16x8*)&pbw[q * 72 + seg * 16];
  *(s16x8*)(dst + 8) = *(const s16x8*)&pbw[q * 72 + seg * 16 + 8];
}

__global__ __launch_bounds__(512, 4) void attn_kernel(const unsigned short* __restrict__ Q,
                                                      const unsigned short* __restrict__ Kg,
                                                      const unsigned short* __restrict__ Vt,
                                                      unsigned short* __restrict__ O,
                                                      const int* __restrict__ pad,
                                                      const int* __restrict__ tmask,
                                                      const int* __restrict__ flags) {
  __shared__ unsigned short kb[2][64 * 72];   // 18.0 KiB
  __shared__ unsigned short vb[2][64 * 72];   // 18.0 KiB
  __shared__ unsigned short pb[8][16 * 72];   // 18.0 KiB (wave-private P scratch)

  const int ip = blockIdx.x, bh = blockIdx.y;
  const int b = bh >> 4, hh = bh & 15;
  const int tid = threadIdx.x, w = tid >> 6, lane = tid & 63, lo = lane & 15, hi = lane >> 4;
  const int qtA = ip, qtB = 15 - ip;
  const int qw0A = qtA * 128 + w * 16, qw0B = qtB * 128 + w * 16;
  const int ktA = 2 * qtA + 1;       // last K-tile index tile A needs (any wave)
  const int ktmax = 2 * qtB + 2;     // number of K-tiles tile B needs
  const bool trivial = flags[0] == 0;

  const unsigned short* Qb = Q + (size_t)bh * Sseq * HSn;
  const unsigned short* Kb = Kg + (size_t)bh * Sseq * HSn;
  const unsigned short* Vb = Vt + (size_t)bh * HSn * Sseq;

  // Q fragments (B-operand of swapped QK^T)
  s16x8 qfA[2], qfB[2];
#pragma unroll
  for (int kk = 0; kk < 2; ++kk) {
    qfA[kk] = *(const s16x8*)&Qb[(size_t)(qw0A + lo) * HSn + kk * 32 + hi * 8];
    qfB[kk] = *(const s16x8*)&Qb[(size_t)(qw0B + lo) * HSn + kk * 32 + hi * 8];
  }

  s16x8 ones;
#pragma unroll
  for (int j = 0; j < 8; ++j) ones[j] = (short)0x3F80; // bf16 1.0

  f32x4 oaccA[4] = {}, oaccB[4] = {};
  f32x4 laccA = {}, laccB = {};
  float mrunA = -3e38f, mrunB = -3e38f;

  // staging: waves 0-3 handle K, waves 4-7 handle V (256 threads each)
  const int shalf = tid >> 8, st_t = tid & 255;
  const int sr = st_t >> 2, sc = (st_t & 3) * 16;

  // prologue: stage kt=0 into buffer 0
  s16x8 r0, r1;
  if (shalf == 0) {
    const unsigned short* gk = Kb + (size_t)sr * HSn + sc;
    r0 = *(const s16x8*)gk; r1 = *(const s16x8*)(gk + 8);
    *(s16x8*)&kb[0][sr * 72 + sc] = r0; *(s16x8*)&kb[0][sr * 72 + sc + 8] = r1;
  } else {
    const unsigned short* gv = Vb + (size_t)sr * Sseq + sc;
    r0 = *(const s16x8*)gv; r1 = *(const s16x8*)(gv + 8);
    *(s16x8*)&vb[0][sr * 72 + sc] = r0; *(s16x8*)&vb[0][sr * 72 + sc + 8] = r1;
  }
  __syncthreads();

  for (int kt = 0; kt < ktmax; ++kt) {
    const int cur = kt & 1, k0 = kt * 64;
    const bool pre = (kt + 1 < ktmax);
    if (pre) { // issue next-tile loads early; latency hides under compute
      const int k1 = k0 + 64;
      if (shalf == 0) {
        const unsigned short* gk = Kb + (size_t)(k1 + sr) * HSn + sc;
        r0 = *(const s16x8*)gk; r1 = *(const s16x8*)(gk + 8);
      } else {
        const unsigned short* gv = Vb + (size_t)sr * Sseq + k1 + sc;
        r0 = *(const s16x8*)gv; r1 = *(const s16x8*)(gv + 8);
      }
    }
    const unsigned short* kbc = kb[cur];
    const unsigned short* vbc = vb[cur];
    if (kt <= ktA)
      attn_unit16(kbc, vbc, qfA, oaccA, laccA, mrunA, ones, pb[w],
                  k0, qw0A, lo, hi, b, pad, tmask, trivial);
    attn_unit16(kbc, vbc, qfB, oaccB, laccB, mrunB, ones, pb[w],
                k0, qw0B, lo, hi, b, pad, tmask, trivial);
    if (pre) { // write-late into the other buffer
      const int nb = cur ^ 1;
      if (shalf == 0) {
        *(s16x8*)&kb[nb][sr * 72 + sc] = r0; *(s16x8*)&kb[nb][sr * 72 + sc + 8] = r1;
      } else {
        *(s16x8*)&vb[nb][sr * 72 + sc] = r0; *(s16x8*)&vb[nb][sr * 72 + sc + 8] = r1;
      }
    }
    __syncthreads();
  }

  attn_epi16(oaccA, laccA[0], pb[w], O, b, hh, qw0A, lane, lo, hi);
  attn_epi16(oaccB, laccB[0], pb[w], O, b, hh, qw0B, lane, lo, hi);
}

extern "C" void kernel_launch(void* const* d_in, const int* in_sizes, int n_in,
                              void* d_out, int out_size, void* d_ws, size_t ws_size,
                              hipStream_t stream) {
  const float* x = (const float*)d_in[0];
  const float* y = (const float*)d_in[1];
  const int* pad = (const int*)d_in[2];
  const int* tmask = (const int*)d_in[3];
  const float* Wq = (const float*)d_in[4];
  const float* Wk = (const float*)d_in[5];
  const float* Wv = (const float*)d_in[6];
  const float* Wp = (const float*)d_in[7];
  const float* bp = (const float*)d_in[8];

  char* ws = (char*)d_ws;
  unsigned short* xbf = (unsigned short*)(ws + OFF_XBF);
  unsigned short* ybf = (unsigned short*)(ws + OFF_YBF);
  unsigned short* wqb = (unsigned short*)(ws + OFF_WQ);
  unsigned short* wkb = (unsigned short*)(ws + OFF_WK);
  unsigned short* wvb = (unsigned short*)(ws + OFF_WV);
  unsigned short* wpb = (unsigned short*)(ws + OFF_WP);
  unsigned short* qws = (unsigned short*)(ws + OFF_QWS);
  unsigned short* kws = (unsigned short*)(ws + OFF_KWS);
  unsigned short* vtw = (unsigned short*)(ws + OFF_VTWS);
  unsigned short* ows = (unsigned short*)(ws + OFF_OWS);
  int* flags = (int*)(ws + OFF_FLAG);

  hipMemsetAsync(flags, 0, 4, stream);
  cvt_all<<<12296, 256, 0, stream>>>(x, y, Wq, Wk, Wv, Wp, pad, tmask, ws, flags);

  q_gemm<<<dim3(64, 8), 256, 0, stream>>>(ybf, wqb, qws);
  kv_gemm<<<dim3(64, 8), 256, 0, stream>>>(xbf, wkb, wvb, kws, vtw);

  attn_kernel<<<dim3(8, 64), 512, 0, stream>>>(qws, kws, vtw, ows, pad, tmask, flags);

  gemm_p<<<dim3(64, 8), 256, 0, stream>>>(ows, wpb, (float*)d_out, bp);
}